// Round 10
// baseline (669.422 us; speedup 1.0000x reference)
//
#include <hip/hip_runtime.h>
#include <hip/hip_bf16.h>

#define NB 8
#define NN 4096
#define KK 20
#define CFEAT 64
#define CCAT 144
#define CHN 64
#define NHEAD 8
#define DKK 32
#define DVV 16
#define NQC 256
#define EPSV 1e-5f
#define BNTOT (NB*NN)      /* 32768 */
#define ITEMS (BNTOT*KK)   /* 655360 */

typedef unsigned short ushort_t;
typedef __attribute__((ext_vector_type(8))) short bf16x8;
typedef __attribute__((ext_vector_type(4))) float f32x4;

// ---------- helpers ----------

__device__ __forceinline__ float wred(float v) {
#pragma unroll
  for (int off = 32; off > 0; off >>= 1) v += __shfl_down(v, off);
  return v;
}

__device__ __forceinline__ ushort_t f2bf(float f) {
  unsigned u = __float_as_uint(f);
  return (ushort_t)((u + 0x7fffu + ((u >> 16) & 1u)) >> 16);
}
__device__ __forceinline__ float bf2f(ushort_t h) {
  return __uint_as_float(((unsigned)h) << 16);
}

// identical across all knn phases so d is bit-identical
__device__ __forceinline__ float pdist(float4 me, float4 p) {
  float dot = fmaf(me.x, p.x, fmaf(me.y, p.y, me.z * p.z));
  return fmaf(-2.f, dot, me.w + p.w);
}

__device__ __forceinline__ void insert20(float* bd, float d) {
#pragma unroll
  for (int j = KK - 1; j >= 1; --j)
    bd[j] = __builtin_amdgcn_fmed3f(d, bd[j - 1], bd[j]);
  bd[0] = fminf(bd[0], d);
}

// build 16 channels of fcat (fallback path)
__device__ __forceinline__ void build_chunk(int ch,
    const float* __restrict__ fme, const float* __restrict__ fnb,
    float rx, float ry, float rz, const float* __restrict__ Wh, float* fc)
{
  if (ch < 4) {
    int c0 = ch * 16;
#pragma unroll
    for (int j = 0; j < 16; j += 4) {
      float4 a = *(const float4*)(fnb + c0 + j);
      float4 m = *(const float4*)(fme + c0 + j);
      fc[j + 0] = a.x - m.x; fc[j + 1] = a.y - m.y;
      fc[j + 2] = a.z - m.z; fc[j + 3] = a.w - m.w;
    }
  } else if (ch < 8) {
    int c0 = (ch - 4) * 16;
#pragma unroll
    for (int j = 0; j < 16; j += 4) {
      float4 m = *(const float4*)(fme + c0 + j);
      fc[j + 0] = m.x; fc[j + 1] = m.y; fc[j + 2] = m.z; fc[j + 3] = m.w;
    }
  } else {
#pragma unroll
    for (int v = 0; v < 16; ++v)
      fc[v] = fmaf(Wh[v * 3], rx, fmaf(Wh[v * 3 + 1], ry, Wh[v * 3 + 2] * rz));
  }
}

template<int NO>
__device__ __forceinline__ void accum_chunk(const float* __restrict__ W, int ch,
                                            const float* fc, float* acc)
{
  const float* wb = W + ch * 16;
#pragma unroll
  for (int o = 0; o < NO; ++o) {
    const float* w = wb + o * CCAT;
#pragma unroll
    for (int j = 0; j < 16; ++j) acc[o] = fmaf(w[j], fc[j], acc[o]);
  }
}

// ---------- shared kernels ----------

// fully-coalesced prep via LDS staging: block = 256 points
__global__ void __launch_bounds__(256) k_prep(const float* __restrict__ x,
                                              float4* __restrict__ xyz4,
                                              float* __restrict__ feat,
                                              float* __restrict__ outp)
{
  __shared__ float lx[256 * 67];
  int t = threadIdx.x;
  size_t base = (size_t)blockIdx.x * 256;
  const float* xb = x + base * 67;
#pragma unroll 4
  for (int j = t; j < 256 * 67; j += 256) lx[j] = xb[j];
  __syncthreads();
  {
    float a = lx[t * 67], b = lx[t * 67 + 1], c = lx[t * 67 + 2];
    xyz4[base + t] = make_float4(a, b, c, a * a + b * b + c * c);
  }
#pragma unroll
  for (int r = 0; r < 3; ++r) {
    int j = r * 256 + t;
    outp[base * 3 + j] = lx[(j / 3) * 67 + (j % 3)];
  }
#pragma unroll 8
  for (int j = t; j < 256 * 64; j += 256)
    feat[base * 64 + j] = lx[(j >> 6) * 67 + 3 + (j & 63)];
}

// ===== SPLIT KNN (LDS-free phases, full occupancy) =====
// phase 1: per (query, segment of 256 pts) sorted top-20 dists -> sbdg
#define KSEG 16
__global__ void __launch_bounds__(256) k_knn1(const float4* __restrict__ xyz4,
                                              float* __restrict__ sbdg)
{
  int bi = blockIdx.x;                  // 2048 = 8b x 64qg x 4sg
  int sg = bi & 3, qg = (bi >> 2) & 63, b = bi >> 8;
  int w = threadIdx.x >> 6, lane = threadIdx.x & 63;
  int seg = sg * 4 + w;                 // wave-uniform
  int n = (qg << 6) + lane;
  const float4* pts = xyz4 + (size_t)b * NN;
  float4 me = pts[n];
  float bd[KK];
#pragma unroll
  for (int j = 0; j < KK; ++j) bd[j] = 3.4e38f;
  int m0 = seg << 8;
  float4 pc0 = pts[m0], pc1 = pts[m0 + 1], pc2 = pts[m0 + 2], pc3 = pts[m0 + 3];
#pragma unroll 1
  for (int m = m0; m < m0 + 256; m += 4) {
    float4 pn0 = pts[m + 4], pn1 = pts[m + 5], pn2 = pts[m + 6], pn3 = pts[m + 7];
    float d0 = pdist(me, pc0);
    float d1 = pdist(me, pc1);
    float d2 = pdist(me, pc2);
    float d3 = pdist(me, pc3);
    insert20(bd, d0);
    insert20(bd, d1);
    insert20(bd, d2);
    insert20(bd, d3);
    pc0 = pn0; pc1 = pn1; pc2 = pn2; pc3 = pn3;
  }
  float* dst = sbdg + ((size_t)(b * NN + n) * KSEG + seg) * KK;
#pragma unroll
  for (int j = 0; j < KK; ++j) dst[j] = bd[j];
}

// tau = 20th smallest of the union (per query: 320 values)
__global__ void __launch_bounds__(256) k_knn2(const float* __restrict__ sbdg,
                                              float* __restrict__ taug)
{
  int bn = blockIdx.x * 256 + threadIdx.x;   // grid 128
  const float* base = sbdg + (size_t)bn * (KSEG * KK);
  float bd[KK];
#pragma unroll
  for (int j = 0; j < KK; ++j) bd[j] = 3.4e38f;
#pragma unroll 1
  for (int m = 0; m < KSEG * KK; m += 4) {
    float4 v = *(const float4*)(base + m);
    insert20(bd, v.x);
    insert20(bd, v.y);
    insert20(bd, v.z);
    insert20(bd, v.w);
  }
  taug[bn] = bd[19];
}

// phase 2: rescan, scatter d<tau via global per-query counters
__global__ void __launch_bounds__(256) k_knn3(const float4* __restrict__ xyz4,
                                              const float* __restrict__ taug,
                                              int* __restrict__ idxb,
                                              int* __restrict__ gscnt,
                                              int* __restrict__ gstcnt,
                                              int* __restrict__ gsties)
{
  int bi = blockIdx.x;
  int sg = bi & 3, qg = (bi >> 2) & 63, b = bi >> 8;
  int w = threadIdx.x >> 6, lane = threadIdx.x & 63;
  int seg = sg * 4 + w;
  int n = (qg << 6) + lane;
  int bn = b * NN + n;
  const float4* pts = xyz4 + (size_t)b * NN;
  float4 me = pts[n];
  float tau = taug[bn];
  size_t obase = (size_t)bn * KK;
  int m0 = seg << 8;
#pragma unroll 2
  for (int m = m0; m < m0 + 256; ++m) {
    float4 p = pts[m];
    float d = pdist(me, p);
    if (d < tau) {
      int slot = atomicAdd(&gscnt[bn], 1);
      idxb[obase + slot] = m;
    } else if (d == tau) {
      int ts_ = atomicAdd(&gstcnt[bn], 1);
      if (ts_ < 16) gsties[bn * 16 + ts_] = m;
    }
  }
}

// tie resolution: fill remaining slots with lowest tie indices in order
__global__ void __launch_bounds__(256) k_knn4(const int* __restrict__ gscnt,
                                              const int* __restrict__ gstcnt,
                                              const int* __restrict__ gsties,
                                              int* __restrict__ idxb)
{
  int bn = blockIdx.x * 256 + threadIdx.x;   // grid 128
  int c1 = gscnt[bn];                        // <= 19
  int tc = min(gstcnt[bn], 16);
  int need = KK - c1;
  size_t ob = (size_t)bn * KK;
  int last = -1;
#pragma unroll 1
  for (int r = 0; r < need; ++r) {
    int best = 0x7fffffff;
    for (int u = 0; u < tc; ++u) {
      int mv = gsties[bn * 16 + u];
      if (mv > last && mv < best) best = mv;
    }
    if (best == 0x7fffffff) best = 0;
    idxb[ob + c1 + r] = best;
    last = best;
  }
}

// ===== single-kernel KNN (fallback when ws too small for split) =====
#define KNQ 64
#define KNS 12
__global__ void __launch_bounds__(768) k_knn(const float4* __restrict__ xyz4,
                                             int* __restrict__ idxb)
{
  __shared__ float sbd[KNS][KNQ][21];
  __shared__ float stau[KNQ];
  __shared__ int   scnt[KNQ];
  __shared__ int   stcnt[KNQ];
  __shared__ int   sties[KNQ * 16];
  int t = threadIdx.x;
  int q = t & 63, s = t >> 6;
  int b = blockIdx.x >> 6;
  int n = ((blockIdx.x & 63) << 6) + q;
  const float4* pts = xyz4 + (size_t)b * NN;
  float4 me = pts[n];
  if (t < KNQ) { scnt[t] = 0; stcnt[t] = 0; }
  int m_lo = (s * NN) / KNS;
  int m_hi = ((s + 1) * NN) / KNS;
  int m4e = m_lo + ((m_hi - m_lo) & ~3);
  float bd[KK];
#pragma unroll
  for (int j = 0; j < KK; ++j) bd[j] = 3.4e38f;
  float4 pc0 = pts[m_lo], pc1 = pts[m_lo + 1], pc2 = pts[m_lo + 2], pc3 = pts[m_lo + 3];
#pragma unroll 1
  for (int m = m_lo; m < m4e; m += 4) {
    float4 pn0 = pts[m + 4], pn1 = pts[m + 5], pn2 = pts[m + 6], pn3 = pts[m + 7];
    float d0 = pdist(me, pc0);
    float d1 = pdist(me, pc1);
    float d2 = pdist(me, pc2);
    float d3 = pdist(me, pc3);
    insert20(bd, d0);
    insert20(bd, d1);
    insert20(bd, d2);
    insert20(bd, d3);
    pc0 = pn0; pc1 = pn1; pc2 = pn2; pc3 = pn3;
  }
#pragma unroll 1
  for (int m = m4e; m < m_hi; ++m) {
    float d = pdist(me, pts[m]);
    insert20(bd, d);
  }
#pragma unroll
  for (int j = 0; j < KK; ++j) sbd[s][q][j] = bd[j];
  sbd[s][q][KK] = 3.4e38f;
  __syncthreads();
  if (t < KNQ) {
    int ia[KNS];
#pragma unroll
    for (int ss = 0; ss < KNS; ++ss) ia[ss] = 0;
    float tau = 0.f;
#pragma unroll 1
    for (int r = 0; r < KK; ++r) {
      float best = 3.5e38f; int bs = 0;
#pragma unroll
      for (int ss = 0; ss < KNS; ++ss) {
        float v = sbd[ss][t][ia[ss]];
        if (v < best) { best = v; bs = ss; }
      }
      ia[bs]++;
      tau = best;
    }
    stau[t] = tau;
  }
  __syncthreads();
  float tau = stau[q];
  size_t obase = ((size_t)b * NN + n) * KK;
#pragma unroll 2
  for (int m = m_lo; m < m_hi; ++m) {
    float4 p = pts[m];
    float d = pdist(me, p);
    if (d < tau) {
      int slot = atomicAdd(&scnt[q], 1);
      idxb[obase + slot] = m;
    } else if (d == tau) {
      int ts_ = atomicAdd(&stcnt[q], 1);
      if (ts_ < 16) sties[q * 16 + ts_] = m;
    }
  }
  __syncthreads();
  if (t < KNQ) {
    int c1 = scnt[t];
    int tc = min(stcnt[t], 16);
    int need = KK - c1;
    size_t ob = ((size_t)b * NN + (((blockIdx.x & 63) << 6) + t)) * KK;
    int last = -1;
#pragma unroll 1
    for (int r = 0; r < need; ++r) {
      int best = 0x7fffffff;
      for (int u = 0; u < tc; ++u) {
        int mv = sties[t * 16 + u];
        if (mv > last && mv < best) best = mv;
      }
      if (best == 0x7fffffff) best = 0;
      idxb[ob + c1 + r] = best;
      last = best;
    }
  }
}

__global__ void k_red1(const float* __restrict__ st1, const float* __restrict__ g1,
                       const float* __restrict__ b1, const float* __restrict__ gv,
                       const float* __restrict__ bv, float* __restrict__ par)
{
  int o = threadIdx.x;
  const float inv = 1.f / (float)ITEMS;
  if (o < 64) {
    float s = 0.f, s2 = 0.f;
    for (int j = 0; j < 64; ++j) { s += st1[j * 160 + o]; s2 += st1[j * 160 + 64 + o]; }
    float mu = s * inv, var = s2 * inv - mu * mu;
    float a = g1[o] * rsqrtf(var + EPSV);
    par[o] = a; par[64 + o] = b1[o] - mu * a;
  } else if (o < 80) {
    int v = o - 64;
    float s = 0.f, s2 = 0.f;
    for (int j = 0; j < 64; ++j) { s += st1[j * 160 + 128 + v]; s2 += st1[j * 160 + 144 + v]; }
    float mu = s * inv, var = s2 * inv - mu * mu;
    float a = gv[v] * rsqrtf(var + EPSV);
    par[128 + v] = a; par[144 + v] = bv[v] - mu * a;
  }
}

__global__ void k_red2(const float* __restrict__ st2, const float* __restrict__ g2,
                       const float* __restrict__ b2, float* __restrict__ par)
{
  int o = threadIdx.x; // 64
  float s = 0.f, s2 = 0.f;
  for (int j = 0; j < 64; ++j) { s += st2[j * 128 + o]; s2 += st2[j * 128 + 64 + o]; }
  const float inv = 1.f / (float)ITEMS;
  float mu = s * inv, var = s2 * inv - mu * mu;
  float a = g2[o] * rsqrtf(var + EPSV);
  par[160 + o] = a; par[224 + o] = b2[o] - mu * a;
}

// ---------- MFMA PATH ----------

__global__ void __launch_bounds__(256, 2) k_g1(
    const float4* __restrict__ xyz4, const float* __restrict__ feat,
    const int* __restrict__ idxb, const float* __restrict__ W1,
    const float* __restrict__ Wv, const float* __restrict__ Wk,
    const float* __restrict__ Wh, float* __restrict__ st1,
    ushort_t* __restrict__ t1g, ushort_t* __restrict__ akg,
    ushort_t* __restrict__ tvg)
{
  __shared__ ushort_t lds[4][16][120];
  int tid = threadIdx.x;
  int w = tid >> 6, lane = tid & 63;
  int m = lane & 15, quad = lane >> 4;

  bf16x8 Bf[7][5];
#pragma unroll
  for (int nt = 0; nt < 7; ++nt) {
    const float* wrow = (nt < 4) ? (W1 + (nt * 16 + m) * CCAT)
                      : (nt == 4) ? (Wv + m * CCAT)
                      : (Wk + ((nt - 5) * 16 + m) * CCAT);
#pragma unroll
    for (int ks = 0; ks < 5; ++ks) {
      int c0 = ks * 32 + quad * 8;
      bf16x8 f;
      if (c0 < 144) {
        float4 u = *(const float4*)(wrow + c0);
        float4 v = *(const float4*)(wrow + c0 + 4);
        f[0] = (short)f2bf(u.x); f[1] = (short)f2bf(u.y);
        f[2] = (short)f2bf(u.z); f[3] = (short)f2bf(u.w);
        f[4] = (short)f2bf(v.x); f[5] = (short)f2bf(v.y);
        f[6] = (short)f2bf(v.z); f[7] = (short)f2bf(v.w);
      } else {
#pragma unroll
        for (int j = 0; j < 8; ++j) f[j] = 0;
      }
      Bf[nt][ks] = f;
    }
  }

  float ss[5], sq[5];
#pragma unroll
  for (int i = 0; i < 5; ++i) { ss[i] = 0.f; sq[i] = 0.f; }

#pragma unroll 1
  for (int t = 0; t < 4; ++t) {
    int tile = blockIdx.x * 16 + w * 4 + t;
    int item = tile * 16 + m;
    int bn = item / 20;
    int b = bn >> 12;
    int nb = idxb[item];
    const float* fme = feat + (size_t)bn * CFEAT;
    const float* fnb = feat + ((size_t)b * NN + nb) * CFEAT;
    float4 pm = xyz4[bn];
    float4 pn = xyz4[(size_t)b * NN + nb];
    float rx = pn.x - pm.x, ry = pn.y - pm.y, rz = pn.z - pm.z;

    f32x4 acc[7];
#pragma unroll
    for (int nt = 0; nt < 7; ++nt)
#pragma unroll
      for (int r = 0; r < 4; ++r) acc[nt][r] = 0.f;

#pragma unroll
    for (int ks = 0; ks < 5; ++ks) {
      int c0 = ks * 32 + quad * 8;
      bf16x8 A;
      if (c0 < 64) {
        float4 a0 = *(const float4*)(fnb + c0);
        float4 a1 = *(const float4*)(fnb + c0 + 4);
        float4 m0 = *(const float4*)(fme + c0);
        float4 m1 = *(const float4*)(fme + c0 + 4);
        A[0] = (short)f2bf(a0.x - m0.x); A[1] = (short)f2bf(a0.y - m0.y);
        A[2] = (short)f2bf(a0.z - m0.z); A[3] = (short)f2bf(a0.w - m0.w);
        A[4] = (short)f2bf(a1.x - m1.x); A[5] = (short)f2bf(a1.y - m1.y);
        A[6] = (short)f2bf(a1.z - m1.z); A[7] = (short)f2bf(a1.w - m1.w);
      } else if (c0 < 128) {
        int c = c0 - 64;
        float4 m0 = *(const float4*)(fme + c);
        float4 m1 = *(const float4*)(fme + c + 4);
        A[0] = (short)f2bf(m0.x); A[1] = (short)f2bf(m0.y);
        A[2] = (short)f2bf(m0.z); A[3] = (short)f2bf(m0.w);
        A[4] = (short)f2bf(m1.x); A[5] = (short)f2bf(m1.y);
        A[6] = (short)f2bf(m1.z); A[7] = (short)f2bf(m1.w);
      } else if (c0 < 144) {
        int v0 = c0 - 128;
#pragma unroll
        for (int j = 0; j < 8; ++j) {
          float pv = fmaf(Wh[(v0 + j) * 3], rx,
                     fmaf(Wh[(v0 + j) * 3 + 1], ry, Wh[(v0 + j) * 3 + 2] * rz));
          A[j] = (short)f2bf(pv);
        }
      } else {
#pragma unroll
        for (int j = 0; j < 8; ++j) A[j] = 0;
      }
#pragma unroll
      for (int nt = 0; nt < 7; ++nt)
        acc[nt] = __builtin_amdgcn_mfma_f32_16x16x32_bf16(A, Bf[nt][ks], acc[nt], 0, 0, 0);
    }

#pragma unroll
    for (int nt = 0; nt < 5; ++nt)
#pragma unroll
      for (int r = 0; r < 4; ++r) {
        float v = acc[nt][r];
        ss[nt] += v; sq[nt] += v * v;
      }

#pragma unroll
    for (int nt = 0; nt < 7; ++nt)
#pragma unroll
      for (int r = 0; r < 4; ++r)
        lds[w][quad * 4 + r][nt * 16 + m] = f2bf(acc[nt][r]);
    __syncthreads();

    {
      int it = lane >> 2, sg = lane & 3;
      const uint4* sp = (const uint4*)&lds[w][it][sg * 16];
      uint4 d0 = sp[0], d1 = sp[1];
      *(uint4*)(t1g + (size_t)tile * 1024 + lane * 16) = d0;
      *(uint4*)(t1g + (size_t)tile * 1024 + lane * 16 + 8) = d1;
      const uint4* spk = (const uint4*)&lds[w][it][80 + sg * 8];
      *(uint4*)(akg + (size_t)tile * 512 + lane * 8) = spk[0];
      if (lane < 32) {
        const uint4* spv = (const uint4*)&lds[w][lane >> 1][64 + (lane & 1) * 8];
        *(uint4*)(tvg + (size_t)tile * 256 + lane * 8) = spv[0];
      }
    }
    __syncthreads();
  }

  float* slot = st1 + (blockIdx.x & 63) * 160;
#pragma unroll
  for (int nt = 0; nt < 5; ++nt) {
    float s = ss[nt];
    s += __shfl_xor(s, 16); s += __shfl_xor(s, 32);
    float q = sq[nt];
    q += __shfl_xor(q, 16); q += __shfl_xor(q, 32);
    if (lane < 16) {
      if (nt < 4) {
        atomicAdd(&slot[nt * 16 + lane], s);
        atomicAdd(&slot[64 + nt * 16 + lane], q);
      } else {
        atomicAdd(&slot[128 + lane], s);
        atomicAdd(&slot[144 + lane], q);
      }
    }
  }
}

__global__ void __launch_bounds__(256) k_g2(
    const ushort_t* __restrict__ t1g, const float* __restrict__ W2,
    const float* __restrict__ par, float* __restrict__ st2,
    float* __restrict__ fqpre)
{
  __shared__ ushort_t lds[4][80][68];
  int tid = threadIdx.x;
  int w = tid >> 6, lane = tid & 63;
  int m = lane & 15, quad = lane >> 4;
  int gw = blockIdx.x * 4 + w;

  bf16x8 Bf[4][2];
#pragma unroll
  for (int nt = 0; nt < 4; ++nt) {
    const float* wrow = W2 + (nt * 16 + m) * CHN;
#pragma unroll
    for (int ks = 0; ks < 2; ++ks) {
      int c0 = ks * 32 + quad * 8;
      float4 u = *(const float4*)(wrow + c0);
      float4 v = *(const float4*)(wrow + c0 + 4);
      bf16x8 f;
      f[0] = (short)f2bf(u.x); f[1] = (short)f2bf(u.y);
      f[2] = (short)f2bf(u.z); f[3] = (short)f2bf(u.w);
      f[4] = (short)f2bf(v.x); f[5] = (short)f2bf(v.y);
      f[6] = (short)f2bf(v.z); f[7] = (short)f2bf(v.w);
      Bf[nt][ks] = f;
    }
  }
  float pa[2][8], pb[2][8];
#pragma unroll
  for (int ks = 0; ks < 2; ++ks) {
    int c0 = ks * 32 + quad * 8;
    float4 a0 = *(const float4*)(par + c0);
    float4 a1 = *(const float4*)(par + c0 + 4);
    float4 b0 = *(const float4*)(par + 64 + c0);
    float4 b1 = *(const float4*)(par + 64 + c0 + 4);
    pa[ks][0] = a0.x; pa[ks][1] = a0.y; pa[ks][2] = a0.z; pa[ks][3] = a0.w;
    pa[ks][4] = a1.x; pa[ks][5] = a1.y; pa[ks][6] = a1.z; pa[ks][7] = a1.w;
    pb[ks][0] = b0.x; pb[ks][1] = b0.y; pb[ks][2] = b0.z; pb[ks][3] = b0.w;
    pb[ks][4] = b1.x; pb[ks][5] = b1.y; pb[ks][6] = b1.z; pb[ks][7] = b1.w;
  }

  float ss[4] = {0.f, 0.f, 0.f, 0.f}, sq[4] = {0.f, 0.f, 0.f, 0.f};

#pragma unroll 1
  for (int t5 = 0; t5 < 5; ++t5) {
    int tile = gw * 5 + t5;
    int item = tile * 16 + m;
    f32x4 acc[4];
#pragma unroll
    for (int nt = 0; nt < 4; ++nt)
#pragma unroll
      for (int r = 0; r < 4; ++r) acc[nt][r] = 0.f;
#pragma unroll
    for (int ks = 0; ks < 2; ++ks) {
      const ushort_t* tp = t1g + (size_t)item * 64 + ks * 32 + quad * 8;
      uint4 raw = *(const uint4*)tp;
      unsigned rw[4] = {raw.x, raw.y, raw.z, raw.w};
      bf16x8 A;
#pragma unroll
      for (int i = 0; i < 4; ++i) {
        float lo = bf2f((ushort_t)(rw[i] & 0xffffu));
        float hi = bf2f((ushort_t)(rw[i] >> 16));
        float h0 = fmaxf(fmaf(lo, pa[ks][2 * i], pb[ks][2 * i]), 0.f);
        float h1 = fmaxf(fmaf(hi, pa[ks][2 * i + 1], pb[ks][2 * i + 1]), 0.f);
        A[2 * i] = (short)f2bf(h0);
        A[2 * i + 1] = (short)f2bf(h1);
      }
#pragma unroll
      for (int nt = 0; nt < 4; ++nt)
        acc[nt] = __builtin_amdgcn_mfma_f32_16x16x32_bf16(A, Bf[nt][ks], acc[nt], 0, 0, 0);
    }
#pragma unroll
    for (int nt = 0; nt < 4; ++nt)
#pragma unroll
      for (int r = 0; r < 4; ++r) {
        float v = acc[nt][r];
        ss[nt] += v; sq[nt] += v * v;
        lds[w][t5 * 16 + quad * 4 + r][nt * 16 + m] = f2bf(v);
      }
  }
  __syncthreads();

  {
    int bnl = lane >> 4;
    int chb = (lane & 15) * 4;
    float mx0 = -3.4e38f, mx1 = -3.4e38f, mx2 = -3.4e38f, mx3 = -3.4e38f;
    float mn0 = 3.4e38f, mn1 = 3.4e38f, mn2 = 3.4e38f, mn3 = 3.4e38f;
#pragma unroll
    for (int j = 0; j < KK; ++j) {
      const uint2 rv = *(const uint2*)&lds[w][bnl * 20 + j][chb];
      float v0 = bf2f((ushort_t)(rv.x & 0xffffu));
      float v1 = bf2f((ushort_t)(rv.x >> 16));
      float v2 = bf2f((ushort_t)(rv.y & 0xffffu));
      float v3 = bf2f((ushort_t)(rv.y >> 16));
      mx0 = fmaxf(mx0, v0); mn0 = fminf(mn0, v0);
      mx1 = fmaxf(mx1, v1); mn1 = fminf(mn1, v1);
      mx2 = fmaxf(mx2, v2); mn2 = fminf(mn2, v2);
      mx3 = fmaxf(mx3, v3); mn3 = fminf(mn3, v3);
    }
    int bn = gw * 4 + bnl;
    *(float4*)(fqpre + (size_t)bn * 128 + chb) = make_float4(mx0, mx1, mx2, mx3);
    *(float4*)(fqpre + (size_t)bn * 128 + 64 + chb) = make_float4(mn0, mn1, mn2, mn3);
  }

  float* slot = st2 + (blockIdx.x & 63) * 128;
#pragma unroll
  for (int nt = 0; nt < 4; ++nt) {
    float s = ss[nt];
    s += __shfl_xor(s, 16); s += __shfl_xor(s, 32);
    float q = sq[nt];
    q += __shfl_xor(q, 16); q += __shfl_xor(q, 32);
    if (lane < 16) {
      atomicAdd(&slot[nt * 16 + lane], s);
      atomicAdd(&slot[64 + nt * 16 + lane], q);
    }
  }
}

#define P3P 16
__global__ void __launch_bounds__(320, 2) k_p3s(
    const ushort_t* __restrict__ akg, const ushort_t* __restrict__ tvg,
    const float* __restrict__ par, __hip_bfloat16* __restrict__ kvg)
{
  __shared__ float sl[P3P][KK][DKK + 1];
  __shared__ float sv[P3P][KK][DVV + 1];
  __shared__ float sm[P3P][DKK], ssi[P3P][DKK];
  int tid = threadIdx.x;
  int p = tid / KK, k = tid - p * KK;
  size_t item = (size_t)(blockIdx.x * P3P + p) * KK + k;
  const unsigned* ap = (const unsigned*)(akg + item * DKK);
#pragma unroll
  for (int i = 0; i < DKK / 2; ++i) {
    unsigned wv = ap[i];
    sl[p][k][2 * i]     = __uint_as_float(wv << 16);
    sl[p][k][2 * i + 1] = __uint_as_float(wv & 0xffff0000u);
  }
  const unsigned* vp = (const unsigned*)(tvg + item * DVV);
#pragma unroll
  for (int i = 0; i < DVV / 2; ++i) {
    unsigned wv = vp[i];
    float lo = __uint_as_float(wv << 16);
    float hi = __uint_as_float(wv & 0xffff0000u);
    sv[p][k][2 * i]     = fmaf(lo, par[128 + 2 * i],     par[144 + 2 * i]);
    sv[p][k][2 * i + 1] = fmaf(hi, par[128 + 2 * i + 1], par[144 + 2 * i + 1]);
  }
  __syncthreads();
  for (int pd = tid; pd < P3P * DKK; pd += 320) {
    int pp = pd >> 5, d = pd & 31;
    float m = -1e30f;
#pragma unroll
    for (int q = 0; q < KK; ++q) m = fmaxf(m, sl[pp][q][d]);
    float S = 0.f;
#pragma unroll
    for (int q = 0; q < KK; ++q) S += __expf(sl[pp][q][d] - m);
    sm[pp][d] = m; ssi[pp][d] = 1.f / S;
  }
  __syncthreads();
  for (int pd = tid; pd < P3P * DKK; pd += 320) {
    int pp = pd >> 5, d = pd & 31;
    float m = sm[pp][d], Si = ssi[pp][d];
    float a[DVV];
#pragma unroll
    for (int v = 0; v < DVV; ++v) a[v] = 0.f;
#pragma unroll
    for (int q = 0; q < KK; ++q) {
      float wgt = __expf(sl[pp][q][d] - m) * Si;
#pragma unroll
      for (int v = 0; v < DVV; ++v) a[v] = fmaf(wgt, sv[pp][q][v], a[v]);
    }
    __hip_bfloat162* dst = (__hip_bfloat162*)
        (kvg + ((size_t)(blockIdx.x * P3P + pp) * DKK + d) * DVV);
#pragma unroll
    for (int v = 0; v < DVV; v += 2) {
      float2 f2; f2.x = a[v]; f2.y = a[v + 1];
      dst[v >> 1] = __float22bfloat162_rn(f2);
    }
  }
}

__global__ void __launch_bounds__(256) k_gq(
    const float* __restrict__ fqpre, const float* __restrict__ Wq,
    const float* __restrict__ par, float* __restrict__ stq,
    float* __restrict__ q2g)
{
  int tid = threadIdx.x;
  int w = tid >> 6, lane = tid & 63;
  int m = lane & 15, quad = lane >> 4;
  int nt0 = (w & 1) * 8;
  int mt = blockIdx.x * 2 + (w >> 1);

  bf16x8 Bf[8][2];
#pragma unroll
  for (int nt = 0; nt < 8; ++nt) {
    const float* wrow = Wq + ((nt0 + nt) * 16 + m) * CHN;
#pragma unroll
    for (int ks = 0; ks < 2; ++ks) {
      int c0 = ks * 32 + quad * 8;
      float4 u = *(const float4*)(wrow + c0);
      float4 v = *(const float4*)(wrow + c0 + 4);
      bf16x8 f;
      f[0] = (short)f2bf(u.x); f[1] = (short)f2bf(u.y);
      f[2] = (short)f2bf(u.z); f[3] = (short)f2bf(u.w);
      f[4] = (short)f2bf(v.x); f[5] = (short)f2bf(v.y);
      f[6] = (short)f2bf(v.z); f[7] = (short)f2bf(v.w);
      Bf[nt][ks] = f;
    }
  }

  f32x4 acc[8];
#pragma unroll
  for (int nt = 0; nt < 8; ++nt)
#pragma unroll
    for (int r = 0; r < 4; ++r) acc[nt][r] = 0.f;

  int item = mt * 16 + m;
  const float* fp = fqpre + (size_t)item * 128;
#pragma unroll
  for (int ks = 0; ks < 2; ++ks) {
    int c0 = ks * 32 + quad * 8;
    float mxv[8], mnv[8], av[8], bv[8];
    *(float4*)&mxv[0] = *(const float4*)(fp + c0);
    *(float4*)&mxv[4] = *(const float4*)(fp + c0 + 4);
    *(float4*)&mnv[0] = *(const float4*)(fp + 64 + c0);
    *(float4*)&mnv[4] = *(const float4*)(fp + 64 + c0 + 4);
    *(float4*)&av[0] = *(const float4*)(par + 160 + c0);
    *(float4*)&av[4] = *(const float4*)(par + 160 + c0 + 4);
    *(float4*)&bv[0] = *(const float4*)(par + 224 + c0);
    *(float4*)&bv[4] = *(const float4*)(par + 224 + c0 + 4);
    bf16x8 A;
#pragma unroll
    for (int j = 0; j < 8; ++j) {
      float pick = (av[j] >= 0.f) ? mxv[j] : mnv[j];
      float fq = fmaxf(fmaf(av[j], pick, bv[j]), 0.f);
      A[j] = (short)f2bf(fq);
    }
#pragma unroll
    for (int nt = 0; nt < 8; ++nt)
      acc[nt] = __builtin_amdgcn_mfma_f32_16x16x32_bf16(A, Bf[nt][ks], acc[nt], 0, 0, 0);
  }

  float* slot = stq + (blockIdx.x & 63) * 512;
#pragma unroll
  for (int nt = 0; nt < 8; ++nt) {
    int o = (nt0 + nt) * 16 + m;
    float s = 0.f, q = 0.f;
#pragma unroll
    for (int r = 0; r < 4; ++r) {
      float v = acc[nt][r];
      q2g[(size_t)(mt * 16 + quad * 4 + r) * NQC + o] = v;
      s += v; q += v * v;
    }
    s += __shfl_xor(s, 16); s += __shfl_xor(s, 32);
    q += __shfl_xor(q, 16); q += __shfl_xor(q, 32);
    if (lane < 16) {
      atomicAdd(&slot[(nt0 + nt) * 16 + lane], s);
      atomicAdd(&slot[256 + (nt0 + nt) * 16 + lane], q);
    }
  }
}

__global__ void k_redq(const float* __restrict__ stq, const float* __restrict__ gq,
                       const float* __restrict__ bq, float* __restrict__ par)
{
  int o = threadIdx.x; // 256
  float s = 0.f, s2 = 0.f;
  for (int j = 0; j < 64; ++j) { s += stq[j * 512 + o]; s2 += stq[j * 512 + 256 + o]; }
  const float inv = 1.f / (float)BNTOT;
  float mu = s * inv, var = s2 * inv - mu * mu;
  float a = gq[o] * rsqrtf(var + EPSV);
  par[288 + o] = a; par[544 + o] = bq[o] - mu * a;
}

// coalesced attention combine
__global__ void __launch_bounds__(256) k_p4(const float* __restrict__ q2g,
                                            const __hip_bfloat16* __restrict__ kvg,
                                            const float* __restrict__ par,
                                            float* __restrict__ outp)
{
  __shared__ float sq2[NQC][33];
  __shared__ unsigned skv[NQC][33];
  int t = threadIdx.x;
  int b = blockIdx.x >> 7, nc = blockIdx.x & 127;
  int bn0 = (b << 12) | (nc << 5);
#pragma unroll 4
  for (int i = t; i < 32 * NQC; i += 256) {
    int n = i >> 8, o = i & 255;
    float q = q2g[(size_t)(bn0 + n) * NQC + o];
    sq2[o][n] = fmaxf(fmaf(q, par[288 + o], par[544 + o]), 0.f);
  }
  const unsigned* kvp = (const unsigned*)kvg;
#pragma unroll 4
  for (int i = t; i < 32 * 256; i += 256) {
    int n = i >> 8, dv2 = i & 255;
    skv[dv2][n] = kvp[(size_t)(bn0 + n) * 256 + dv2];
  }
  __syncthreads();
  int n = t & 31, h = t >> 5;
  float qr[DKK];
#pragma unroll
  for (int d = 0; d < DKK; ++d) qr[d] = sq2[h * DKK + d][n];
  int n_out = (nc << 5) + n;
  size_t ob = (size_t)BNTOT * 3 + (size_t)(b * 128 + h * 16) * NN + n_out;
#pragma unroll
  for (int vv = 0; vv < DVV; vv += 2) {
    float a0 = 0.f, a1 = 0.f;
#pragma unroll
    for (int d = 0; d < DKK; ++d) {
      unsigned pk = skv[(d * DVV + vv) >> 1][n];
      a0 = fmaf(qr[d], bf2f((ushort_t)(pk & 0xffffu)), a0);
      a1 = fmaf(qr[d], bf2f((ushort_t)(pk >> 16)), a1);
    }
    outp[ob + (size_t)vv * NN] = a0;
    outp[ob + (size_t)(vv + 1) * NN] = a1;
  }
}

// ---------- FALLBACK (round-5 proven path) ----------

__global__ void __launch_bounds__(256, 3) k_s1f(
    const float4* __restrict__ xyz4, const float* __restrict__ feat,
    const int* __restrict__ idxb, const float* __restrict__ W1,
    const float* __restrict__ Wv, const float* __restrict__ Wh,
    float* __restrict__ st1,
    __hip_bfloat16* __restrict__ t1g, __hip_bfloat16* __restrict__ tvg)
{
  int t = blockIdx.x * 256 + threadIdx.x;
  int bn = t / KK, k = t - bn * KK, b = bn >> 12;
  int nb = idxb[(size_t)bn * KK + k];
  const float* fme = feat + (size_t)bn * CFEAT;
  const float* fnb = feat + ((size_t)b * NN + nb) * CFEAT;
  float4 pn = xyz4[(size_t)b * NN + nb];
  float4 pm = xyz4[bn];
  float rx = pn.x - pm.x, ry = pn.y - pm.y, rz = pn.z - pm.z;
  float a1[CHN], av[DVV];
#pragma unroll
  for (int o = 0; o < CHN; ++o) a1[o] = 0.f;
#pragma unroll
  for (int o = 0; o < DVV; ++o) av[o] = 0.f;
#pragma unroll 1
  for (int ch = 0; ch < 9; ++ch) {
    float fc[16];
    build_chunk(ch, fme, fnb, rx, ry, rz, Wh, fc);
    accum_chunk<CHN>(W1, ch, fc, a1);
    accum_chunk<DVV>(Wv, ch, fc, av);
  }
  __hip_bfloat162* t1p = (__hip_bfloat162*)(t1g + (size_t)t * CHN);
#pragma unroll
  for (int o = 0; o < CHN; o += 2) {
    float2 f2; f2.x = a1[o]; f2.y = a1[o + 1];
    t1p[o >> 1] = __float22bfloat162_rn(f2);
  }
  __hip_bfloat162* tvp = (__hip_bfloat162*)(tvg + (size_t)t * DVV);
#pragma unroll
  for (int o = 0; o < DVV; o += 2) {
    float2 f2; f2.x = av[o]; f2.y = av[o + 1];
    tvp[o >> 1] = __float22bfloat162_rn(f2);
  }
  float* slot = st1 + (blockIdx.x & 63) * 160;
  int lane = threadIdx.x & 63;
#pragma unroll
  for (int o = 0; o < CHN; ++o) {
    float s = wred(a1[o]), s2 = wred(a1[o] * a1[o]);
    if (lane == 0) { atomicAdd(&slot[o], s); atomicAdd(&slot[CHN + o], s2); }
  }
#pragma unroll
  for (int o = 0; o < DVV; ++o) {
    float s = wred(av[o]), s2 = wred(av[o] * av[o]);
    if (lane == 0) { atomicAdd(&slot[128 + o], s); atomicAdd(&slot[128 + DVV + o], s2); }
  }
}

__global__ void __launch_bounds__(256, 4) k_skf(
    const float4* __restrict__ xyz4, const float* __restrict__ feat,
    const int* __restrict__ idxb, const float* __restrict__ Wk,
    const float* __restrict__ Wh, __hip_bfloat16* __restrict__ akg)
{
  int t = blockIdx.x * 256 + threadIdx.x;
  int bn = t / KK, k = t - bn * KK, b = bn >> 12;
  int nb = idxb[(size_t)bn * KK + k];
  const float* fme = feat + (size_t)bn * CFEAT;
  const float* fnb = feat + ((size_t)b * NN + nb) * CFEAT;
  float4 pn = xyz4[(size_t)b * NN + nb];
  float4 pm = xyz4[bn];
  float rx = pn.x - pm.x, ry = pn.y - pm.y, rz = pn.z - pm.z;
  float ak[DKK];
#pragma unroll
  for (int o = 0; o < DKK; ++o) ak[o] = 0.f;
#pragma unroll 1
  for (int ch = 0; ch < 9; ++ch) {
    float fc[16];
    build_chunk(ch, fme, fnb, rx, ry, rz, Wh, fc);
    accum_chunk<DKK>(Wk, ch, fc, ak);
  }
  __hip_bfloat162* akp = (__hip_bfloat162*)(akg + (size_t)t * DKK);
#pragma unroll
  for (int o = 0; o < DKK; o += 2) {
    float2 f2; f2.x = ak[o]; f2.y = ak[o + 1];
    akp[o >> 1] = __float22bfloat162_rn(f2);
  }
}

__global__ void __launch_bounds__(256, 4) k_s2f(
    const __hip_bfloat16* __restrict__ t1g, const float* __restrict__ W2,
    const float* __restrict__ par, float* __restrict__ st2)
{
  int t = blockIdx.x * 256 + threadIdx.x;
  const unsigned* tp = (const unsigned*)(t1g + (size_t)t * CHN);
  float h1[CHN];
#pragma unroll
  for (int i = 0; i < CHN / 2; ++i) {
    unsigned w = tp[i];
    float lo = __uint_as_float(w << 16);
    float hi = __uint_as_float(w & 0xffff0000u);
    h1[2 * i]     = fmaxf(fmaf(lo, par[2 * i],     par[64 + 2 * i]),     0.f);
    h1[2 * i + 1] = fmaxf(fmaf(hi, par[2 * i + 1], par[64 + 2 * i + 1]), 0.f);
  }
  float* slot = st2 + (blockIdx.x & 63) * 128;
  int lane = threadIdx.x & 63;
#pragma unroll 1
  for (int o = 0; o < CHN; ++o) {
    const float* w = W2 + o * CHN;
    float c0 = 0.f, c1 = 0.f, c2 = 0.f, c3 = 0.f;
#pragma unroll
    for (int c = 0; c < CHN; c += 4) {
      c0 = fmaf(w[c + 0], h1[c + 0], c0); c1 = fmaf(w[c + 1], h1[c + 1], c1);
      c2 = fmaf(w[c + 2], h1[c + 2], c2); c3 = fmaf(w[c + 3], h1[c + 3], c3);
    }
    float v = (c0 + c1) + (c2 + c3);
    float s = wred(v), s2 = wred(v * v);
    if (lane == 0) { atomicAdd(&slot[o], s); atomicAdd(&slot[64 + o], s2); }
  }
}

__global__ void __launch_bounds__(320, 2) k_p3f(
    const __hip_bfloat16* __restrict__ t1g, const __hip_bfloat16* __restrict__ akg,
    const __hip_bfloat16* __restrict__ tvg, const float* __restrict__ W2,
    const float* __restrict__ par, float* __restrict__ fqg,
    __hip_bfloat16* __restrict__ kvg)
{
  __shared__ float sl[P3P][KK][DKK + 1];
  __shared__ float sv[P3P][KK][DVV + 1];
  __shared__ unsigned sfq[P3P][CHN];
  __shared__ float sm[P3P][DKK], ssi[P3P][DKK];
  int tid = threadIdx.x;
  for (int i = tid; i < P3P * CHN; i += 320) ((unsigned*)sfq)[i] = 0u;
  __syncthreads();
  int p = tid / KK, k = tid - p * KK;
  size_t item = (size_t)(blockIdx.x * P3P + p) * KK + k;
  const unsigned* ap = (const unsigned*)(akg + item * DKK);
#pragma unroll
  for (int i = 0; i < DKK / 2; ++i) {
    unsigned w = ap[i];
    sl[p][k][2 * i]     = __uint_as_float(w << 16);
    sl[p][k][2 * i + 1] = __uint_as_float(w & 0xffff0000u);
  }
  const unsigned* vp = (const unsigned*)(tvg + item * DVV);
#pragma unroll
  for (int i = 0; i < DVV / 2; ++i) {
    unsigned w = vp[i];
    float lo = __uint_as_float(w << 16);
    float hi = __uint_as_float(w & 0xffff0000u);
    sv[p][k][2 * i]     = fmaf(lo, par[128 + 2 * i],     par[144 + 2 * i]);
    sv[p][k][2 * i + 1] = fmaf(hi, par[128 + 2 * i + 1], par[144 + 2 * i + 1]);
  }
  const unsigned* tp = (const unsigned*)(t1g + item * CHN);
  float h1[CHN];
#pragma unroll
  for (int i = 0; i < CHN / 2; ++i) {
    unsigned w = tp[i];
    float lo = __uint_as_float(w << 16);
    float hi = __uint_as_float(w & 0xffff0000u);
    h1[2 * i]     = fmaxf(fmaf(lo, par[2 * i],     par[64 + 2 * i]),     0.f);
    h1[2 * i + 1] = fmaxf(fmaf(hi, par[2 * i + 1], par[64 + 2 * i + 1]), 0.f);
  }
#pragma unroll 1
  for (int o = 0; o < CHN; ++o) {
    const float* w = W2 + o * CHN;
    float c0 = 0.f, c1 = 0.f, c2 = 0.f, c3 = 0.f;
#pragma unroll
    for (int c = 0; c < CHN; c += 4) {
      c0 = fmaf(w[c + 0], h1[c + 0], c0); c1 = fmaf(w[c + 1], h1[c + 1], c1);
      c2 = fmaf(w[c + 2], h1[c + 2], c2); c3 = fmaf(w[c + 3], h1[c + 3], c3);
    }
    float v = (c0 + c1) + (c2 + c3);
    float h2 = fmaxf(fmaf(v, par[160 + o], par[224 + o]), 0.f);
    atomicMax(&sfq[p][o], __float_as_uint(h2));
  }
  __syncthreads();
  for (int i = tid; i < P3P * CHN; i += 320)
    fqg[(size_t)blockIdx.x * (P3P * CHN) + i] = __uint_as_float(sfq[i >> 6][i & 63]);
  for (int pd = tid; pd < P3P * DKK; pd += 320) {
    int pp = pd >> 5, d = pd & 31;
    float m = -1e30f;
#pragma unroll
    for (int q = 0; q < KK; ++q) m = fmaxf(m, sl[pp][q][d]);
    float S = 0.f;
#pragma unroll
    for (int q = 0; q < KK; ++q) S += __expf(sl[pp][q][d] - m);
    sm[pp][d] = m; ssi[pp][d] = 1.f / S;
  }
  __syncthreads();
  for (int pd = tid; pd < P3P * DKK; pd += 320) {
    int pp = pd >> 5, d = pd & 31;
    float m = sm[pp][d], Si = ssi[pp][d];
    float a[DVV];
#pragma unroll
    for (int v = 0; v < DVV; ++v) a[v] = 0.f;
#pragma unroll
    for (int q = 0; q < KK; ++q) {
      float wgt = __expf(sl[pp][q][d] - m) * Si;
#pragma unroll
      for (int v = 0; v < DVV; ++v) a[v] = fmaf(wgt, sv[pp][q][v], a[v]);
    }
    __hip_bfloat162* dst = (__hip_bfloat162*)
        (kvg + ((size_t)(blockIdx.x * P3P + pp) * DKK + d) * DVV);
#pragma unroll
    for (int v = 0; v < DVV; v += 2) {
      float2 f2; f2.x = a[v]; f2.y = a[v + 1];
      dst[v >> 1] = __float22bfloat162_rn(f2);
    }
  }
}

__global__ void __launch_bounds__(128, 2) k_pqf(const float* __restrict__ fqg,
                                                const float* __restrict__ Wq,
                                                float* __restrict__ stq,
                                                float* __restrict__ q2g)
{
  int bn = blockIdx.x * 128 + threadIdx.x;
  float fq[CHN];
#pragma unroll
  for (int c = 0; c < CHN; c += 4) {
    float4 v4 = *(const float4*)(fqg + (size_t)bn * CHN + c);
    fq[c] = v4.x; fq[c + 1] = v4.y; fq[c + 2] = v4.z; fq[c + 3] = v4.w;
  }
  float* slot = stq + (blockIdx.x & 63) * 512;
  int lane = threadIdx.x & 63;
#pragma unroll 1
  for (int o = 0; o < NQC; ++o) {
    const float* w = Wq + o * CHN;
    float a0 = 0.f, a1 = 0.f, a2 = 0.f, a3 = 0.f;
#pragma unroll
    for (int c = 0; c < CHN; c += 4) {
      a0 = fmaf(w[c], fq[c], a0); a1 = fmaf(w[c + 1], fq[c + 1], a1);
      a2 = fmaf(w[c + 2], fq[c + 2], a2); a3 = fmaf(w[c + 3], fq[c + 3], a3);
    }
    float v = (a0 + a1) + (a2 + a3);
    q2g[(size_t)bn * NQC + o] = v;
    float s = wred(v), s2 = wred(v * v);
    if (lane == 0) { atomicAdd(&slot[o], s); atomicAdd(&slot[256 + o], s2); }
  }
}

__global__ void __launch_bounds__(64) k_p4f(const float* __restrict__ q2g,
                                            const __hip_bfloat16* __restrict__ kvg,
                                            const float* __restrict__ par,
                                            float* __restrict__ outp)
{
  __shared__ float sq2[NQC], skv[DKK * DVV];
  int t = threadIdx.x;
  int b = blockIdx.x & 7, n = blockIdx.x >> 3;
  int bn = (b << 12) | n;
#pragma unroll
  for (int j = 0; j < 8; ++j)
    skv[t + 64 * j] = __bfloat162float(kvg[(size_t)bn * 512 + t + 64 * j]);
#pragma unroll
  for (int j = 0; j < 4; ++j) {
    int o = t + 64 * j;
    float v = q2g[(size_t)bn * NQC + o];
    sq2[o] = fmaxf(fmaf(v, par[288 + o], par[544 + o]), 0.f);
  }
  __syncthreads();
#pragma unroll
  for (int j = 0; j < 2; ++j) {
    int ch = t + 64 * j, h = ch >> 4, vv = ch & 15;
    float a = 0.f;
#pragma unroll
    for (int d = 0; d < DKK; ++d) a = fmaf(sq2[h * DKK + d], skv[d * DVV + vv], a);
    outp[(size_t)BNTOT * 3 + ((size_t)(b * 128 + ch)) * NN + n] = a;
  }
}

// ---------- launch ----------

extern "C" void kernel_launch(void* const* d_in, const int* in_sizes, int n_in,
                              void* d_out, int out_size, void* d_ws, size_t ws_size,
                              hipStream_t stream)
{
  const float* x  = (const float*)d_in[0];
  const float* W1 = (const float*)d_in[1];
  const float* g1 = (const float*)d_in[2];
  const float* b1 = (const float*)d_in[3];
  const float* W2 = (const float*)d_in[4];
  const float* g2 = (const float*)d_in[5];
  const float* b2 = (const float*)d_in[6];
  const float* Wv = (const float*)d_in[7];
  const float* gv = (const float*)d_in[8];
  const float* bv = (const float*)d_in[9];
  const float* Wk = (const float*)d_in[10];
  const float* Wq = (const float*)d_in[11];
  const float* gq = (const float*)d_in[12];
  const float* bq = (const float*)d_in[13];
  const float* Wh = (const float*)d_in[14];

  float* ws = (float*)d_ws;
  float4* xyz4 = (float4*)ws;                      // 131072
  float*  feat = ws + 131072;                      // 2097152
  int*    idxb = (int*)(ws + 2228224);             // 655360
  float*  st1  = ws + 2883584;                     // 10240
  float*  st2  = ws + 2893824;                     // 8192
  float*  stq  = ws + 2902016;                     // 32768
  float*  par  = ws + 2934784;                     // 800
  float*  fqg  = ws + 2935584;                     // 2097152
  __hip_bfloat16* kvg = (__hip_bfloat16*)(ws + 5032736);  // 8388608 fw
  float*  outp = (float*)d_out;

  ushort_t* t1g = (ushort_t*)(ws + 13421344);      // 20971520 fw
  ushort_t* akg = (ushort_t*)(ws + 34392864);      // 10485760 fw
  ushort_t* tvg = (ushort_t*)(ws + 44878624);      //  5242880 fw
  float*    fqpre = ws + 50121504;                 //  4194304 fw
  float*    q2g = ws + 13421344;                   // alias t1g (dead after k_g2)

  float* sbdg  = ws + 54315808;                    // 10485760 fw (32768*16*20)
  float* taug  = ws + 64801568;                    // 32768
  int*   gscnt = (int*)(ws + 64834336);            // 32768
  int*   gstcnt= (int*)(ws + 64867104);            // 32768
  int*   gsties= (int*)(ws + 64899872);            // 524288 fw -> end 65424160

  const size_t NEW_NEED = (size_t)54315808 * 4;    // ~217.3 MB (MFMA path)
  const size_t KNN_NEED = (size_t)65424160 * 4;    // ~261.7 MB (split knn)

  hipMemsetAsync(st1, 0, (size_t)(10240 + 8192 + 32768) * sizeof(float), stream);
  k_prep<<<128, 256, 0, stream>>>(x, xyz4, feat, outp);

  if (ws_size >= KNN_NEED) {
    hipMemsetAsync(gscnt, 0, (size_t)65536 * sizeof(int), stream);  // gscnt+gstcnt
    k_knn1<<<2048, 256, 0, stream>>>(xyz4, sbdg);
    k_knn2<<<128, 256, 0, stream>>>(sbdg, taug);
    k_knn3<<<2048, 256, 0, stream>>>(xyz4, taug, idxb, gscnt, gstcnt, gsties);
    k_knn4<<<128, 256, 0, stream>>>(gscnt, gstcnt, gsties, idxb);
  } else {
    k_knn<<<512, 768, 0, stream>>>(xyz4, idxb);
  }

  if (ws_size >= NEW_NEED) {
    k_g1  <<<2560, 256, 0, stream>>>(xyz4, feat, idxb, W1, Wv, Wk, Wh, st1, t1g, akg, tvg);
    k_red1<<<1, 128, 0, stream>>>(st1, g1, b1, gv, bv, par);
    k_g2  <<<2048, 256, 0, stream>>>(t1g, W2, par, st2, fqpre);
    k_red2<<<1, 64, 0, stream>>>(st2, g2, b2, par);
    k_p3s <<<2048, 320, 0, stream>>>(akg, tvg, par, kvg);
    k_gq  <<<1024, 256, 0, stream>>>(fqpre, Wq, par, stq, q2g);
    k_redq<<<1, 256, 0, stream>>>(stq, gq, bq, par);
    k_p4  <<<1024, 256, 0, stream>>>(q2g, kvg, par, outp);
  } else {
    __hip_bfloat16* t1b = (__hip_bfloat16*)t1g;
    __hip_bfloat16* akb = (__hip_bfloat16*)akg;
    __hip_bfloat16* tvb = (__hip_bfloat16*)tvg;
    float* q2f = ws + 34392864;
    k_s1f <<<2560, 256, 0, stream>>>(xyz4, feat, idxb, W1, Wv, Wh, st1, t1b, tvb);
    k_skf <<<2560, 256, 0, stream>>>(xyz4, feat, idxb, Wk, Wh, akb);
    k_red1<<<1, 128, 0, stream>>>(st1, g1, b1, gv, bv, par);
    k_s2f <<<2560, 256, 0, stream>>>(t1b, W2, par, st2);
    k_red2<<<1, 64, 0, stream>>>(st2, g2, b2, par);
    k_p3f <<<2048, 320, 0, stream>>>(t1b, akb, tvb, W2, par, fqg, kvg);
    k_pqf <<<256, 128, 0, stream>>>(fqg, Wq, stq, q2f);
    k_redq<<<1, 256, 0, stream>>>(stq, gq, bq, par);
    k_p4f <<<32768, 64, 0, stream>>>(q2f, kvg, par, outp);
  }
}

// Round 11
// 559.476 us; speedup vs baseline: 1.1965x; 1.1965x over previous
//
#include <hip/hip_runtime.h>
#include <hip/hip_bf16.h>

#define NB 8
#define NN 4096
#define KK 20
#define CFEAT 64
#define CCAT 144
#define CHN 64
#define NHEAD 8
#define DKK 32
#define DVV 16
#define NQC 256
#define EPSV 1e-5f
#define BNTOT (NB*NN)      /* 32768 */
#define ITEMS (BNTOT*KK)   /* 655360 */

typedef unsigned short ushort_t;
typedef __attribute__((ext_vector_type(8))) short bf16x8;
typedef __attribute__((ext_vector_type(4))) float f32x4;

// ---------- helpers ----------

__device__ __forceinline__ float wred(float v) {
#pragma unroll
  for (int off = 32; off > 0; off >>= 1) v += __shfl_down(v, off);
  return v;
}

__device__ __forceinline__ ushort_t f2bf(float f) {
  unsigned u = __float_as_uint(f);
  return (ushort_t)((u + 0x7fffu + ((u >> 16) & 1u)) >> 16);
}
__device__ __forceinline__ float bf2f(ushort_t h) {
  return __uint_as_float(((unsigned)h) << 16);
}

// identical in phase1/phase2 so d is bit-identical
__device__ __forceinline__ float pdist(float4 me, float4 p) {
  float dot = fmaf(me.x, p.x, fmaf(me.y, p.y, me.z * p.z));
  return fmaf(-2.f, dot, me.w + p.w);
}

__device__ __forceinline__ void insert20(float* bd, float d) {
#pragma unroll
  for (int j = KK - 1; j >= 1; --j)
    bd[j] = __builtin_amdgcn_fmed3f(d, bd[j - 1], bd[j]);
  bd[0] = fminf(bd[0], d);
}

// build 16 channels of fcat (fallback path)
__device__ __forceinline__ void build_chunk(int ch,
    const float* __restrict__ fme, const float* __restrict__ fnb,
    float rx, float ry, float rz, const float* __restrict__ Wh, float* fc)
{
  if (ch < 4) {
    int c0 = ch * 16;
#pragma unroll
    for (int j = 0; j < 16; j += 4) {
      float4 a = *(const float4*)(fnb + c0 + j);
      float4 m = *(const float4*)(fme + c0 + j);
      fc[j + 0] = a.x - m.x; fc[j + 1] = a.y - m.y;
      fc[j + 2] = a.z - m.z; fc[j + 3] = a.w - m.w;
    }
  } else if (ch < 8) {
    int c0 = (ch - 4) * 16;
#pragma unroll
    for (int j = 0; j < 16; j += 4) {
      float4 m = *(const float4*)(fme + c0 + j);
      fc[j + 0] = m.x; fc[j + 1] = m.y; fc[j + 2] = m.z; fc[j + 3] = m.w;
    }
  } else {
#pragma unroll
    for (int v = 0; v < 16; ++v)
      fc[v] = fmaf(Wh[v * 3], rx, fmaf(Wh[v * 3 + 1], ry, Wh[v * 3 + 2] * rz));
  }
}

template<int NO>
__device__ __forceinline__ void accum_chunk(const float* __restrict__ W, int ch,
                                            const float* fc, float* acc)
{
  const float* wb = W + ch * 16;
#pragma unroll
  for (int o = 0; o < NO; ++o) {
    const float* w = wb + o * CCAT;
#pragma unroll
    for (int j = 0; j < 16; ++j) acc[o] = fmaf(w[j], fc[j], acc[o]);
  }
}

// ---------- shared kernels ----------

// fully-coalesced prep via LDS staging: block = 256 points
__global__ void __launch_bounds__(256) k_prep(const float* __restrict__ x,
                                              float4* __restrict__ xyz4,
                                              float* __restrict__ feat,
                                              float* __restrict__ outp)
{
  __shared__ float lx[256 * 67];
  int t = threadIdx.x;
  size_t base = (size_t)blockIdx.x * 256;
  const float* xb = x + base * 67;
#pragma unroll 4
  for (int j = t; j < 256 * 67; j += 256) lx[j] = xb[j];
  __syncthreads();
  {
    float a = lx[t * 67], b = lx[t * 67 + 1], c = lx[t * 67 + 2];
    xyz4[base + t] = make_float4(a, b, c, a * a + b * b + c * c);
  }
#pragma unroll
  for (int r = 0; r < 3; ++r) {
    int j = r * 256 + t;
    outp[base * 3 + j] = lx[(j / 3) * 67 + (j % 3)];
  }
#pragma unroll 8
  for (int j = t; j < 256 * 64; j += 256)
    feat[base * 64 + j] = lx[(j >> 6) * 67 + 3 + (j & 63)];
}

// exact K=20 NN. Block = 64 queries x 12 segments (768 thr = 12 waves).
#define KNQ 64
#define KNS 12
__global__ void __launch_bounds__(768) k_knn(const float4* __restrict__ xyz4,
                                             int* __restrict__ idxb)
{
  __shared__ float sbd[KNS][KNQ][21];
  __shared__ float stau[KNQ];
  __shared__ int   scnt[KNQ];
  __shared__ int   stcnt[KNQ];
  __shared__ int   sties[KNQ * 16];
  int t = threadIdx.x;
  int q = t & 63, s = t >> 6;           // s wave-uniform (0..11)
  int b = blockIdx.x >> 6;
  int n = ((blockIdx.x & 63) << 6) + q;
  const float4* pts = xyz4 + (size_t)b * NN;
  float4 me = pts[n];
  if (t < KNQ) { scnt[t] = 0; stcnt[t] = 0; }
  int m_lo = (s * NN) / KNS;
  int m_hi = ((s + 1) * NN) / KNS;
  int m4e = m_lo + ((m_hi - m_lo) & ~3);
  float bd[KK];
#pragma unroll
  for (int j = 0; j < KK; ++j) bd[j] = 3.4e38f;
  float4 pc0 = pts[m_lo], pc1 = pts[m_lo + 1], pc2 = pts[m_lo + 2], pc3 = pts[m_lo + 3];
#pragma unroll 1
  for (int m = m_lo; m < m4e; m += 4) {
    float4 pn0 = pts[m + 4], pn1 = pts[m + 5], pn2 = pts[m + 6], pn3 = pts[m + 7];
    float d0 = pdist(me, pc0);
    float d1 = pdist(me, pc1);
    float d2 = pdist(me, pc2);
    float d3 = pdist(me, pc3);
    insert20(bd, d0);
    insert20(bd, d1);
    insert20(bd, d2);
    insert20(bd, d3);
    pc0 = pn0; pc1 = pn1; pc2 = pn2; pc3 = pn3;
  }
#pragma unroll 1
  for (int m = m4e; m < m_hi; ++m) {
    float d = pdist(me, pts[m]);
    insert20(bd, d);
  }
#pragma unroll
  for (int j = 0; j < KK; ++j) sbd[s][q][j] = bd[j];
  sbd[s][q][KK] = 3.4e38f;
  __syncthreads();
  if (t < KNQ) {
    int ia[KNS];
#pragma unroll
    for (int ss = 0; ss < KNS; ++ss) ia[ss] = 0;
    float tau = 0.f;
#pragma unroll 1
    for (int r = 0; r < KK; ++r) {
      float best = 3.5e38f; int bs = 0;
#pragma unroll
      for (int ss = 0; ss < KNS; ++ss) {
        float v = sbd[ss][t][ia[ss]];
        if (v < best) { best = v; bs = ss; }
      }
      ia[bs]++;
      tau = best;
    }
    stau[t] = tau;
  }
  __syncthreads();
  float tau = stau[q];
  size_t obase = ((size_t)b * NN + n) * KK;
#pragma unroll 2
  for (int m = m_lo; m < m_hi; ++m) {
    float4 p = pts[m];
    float d = pdist(me, p);
    if (d < tau) {
      int slot = atomicAdd(&scnt[q], 1);
      idxb[obase + slot] = m;
    } else if (d == tau) {
      int ts_ = atomicAdd(&stcnt[q], 1);
      if (ts_ < 16) sties[q * 16 + ts_] = m;
    }
  }
  __syncthreads();
  if (t < KNQ) {
    int c1 = scnt[t];
    int tc = min(stcnt[t], 16);
    int need = KK - c1;
    size_t ob = ((size_t)b * NN + (((blockIdx.x & 63) << 6) + t)) * KK;
    int last = -1;
#pragma unroll 1
    for (int r = 0; r < need; ++r) {
      int best = 0x7fffffff;
      for (int u = 0; u < tc; ++u) {
        int mv = sties[t * 16 + u];
        if (mv > last && mv < best) best = mv;
      }
      if (best == 0x7fffffff) best = 0;
      idxb[ob + c1 + r] = best;
      last = best;
    }
  }
}

__global__ void k_red1(const float* __restrict__ st1, const float* __restrict__ g1,
                       const float* __restrict__ b1, const float* __restrict__ gv,
                       const float* __restrict__ bv, float* __restrict__ par)
{
  int o = threadIdx.x;
  const float inv = 1.f / (float)ITEMS;
  if (o < 64) {
    float s = 0.f, s2 = 0.f;
    for (int j = 0; j < 64; ++j) { s += st1[j * 160 + o]; s2 += st1[j * 160 + 64 + o]; }
    float mu = s * inv, var = s2 * inv - mu * mu;
    float a = g1[o] * rsqrtf(var + EPSV);
    par[o] = a; par[64 + o] = b1[o] - mu * a;
  } else if (o < 80) {
    int v = o - 64;
    float s = 0.f, s2 = 0.f;
    for (int j = 0; j < 64; ++j) { s += st1[j * 160 + 128 + v]; s2 += st1[j * 160 + 144 + v]; }
    float mu = s * inv, var = s2 * inv - mu * mu;
    float a = gv[v] * rsqrtf(var + EPSV);
    par[128 + v] = a; par[144 + v] = bv[v] - mu * a;
  }
}

__global__ void k_red2(const float* __restrict__ st2, const float* __restrict__ g2,
                       const float* __restrict__ b2, float* __restrict__ par)
{
  int o = threadIdx.x; // 64
  float s = 0.f, s2 = 0.f;
  for (int j = 0; j < 64; ++j) { s += st2[j * 128 + o]; s2 += st2[j * 128 + 64 + o]; }
  const float inv = 1.f / (float)ITEMS;
  float mu = s * inv, var = s2 * inv - mu * mu;
  float a = g2[o] * rsqrtf(var + EPSV);
  par[160 + o] = a; par[224 + o] = b2[o] - mu * a;
}

// ---------- MFMA PATH ----------

// GEMM1. NOTE: lds is WAVE-PRIVATE (indexed by w) -> no __syncthreads needed;
// same-wave DS ordering + compiler lgkmcnt waits give correctness.
__global__ void __launch_bounds__(256, 2) k_g1(
    const float4* __restrict__ xyz4, const float* __restrict__ feat,
    const int* __restrict__ idxb, const float* __restrict__ W1,
    const float* __restrict__ Wv, const float* __restrict__ Wk,
    const float* __restrict__ Wh, float* __restrict__ st1,
    ushort_t* __restrict__ t1g, ushort_t* __restrict__ akg,
    ushort_t* __restrict__ tvg)
{
  __shared__ ushort_t lds[4][16][120];
  int tid = threadIdx.x;
  int w = tid >> 6, lane = tid & 63;
  int m = lane & 15, quad = lane >> 4;

  bf16x8 Bf[7][5];
#pragma unroll
  for (int nt = 0; nt < 7; ++nt) {
    const float* wrow = (nt < 4) ? (W1 + (nt * 16 + m) * CCAT)
                      : (nt == 4) ? (Wv + m * CCAT)
                      : (Wk + ((nt - 5) * 16 + m) * CCAT);
#pragma unroll
    for (int ks = 0; ks < 5; ++ks) {
      int c0 = ks * 32 + quad * 8;
      bf16x8 f;
      if (c0 < 144) {
        float4 u = *(const float4*)(wrow + c0);
        float4 v = *(const float4*)(wrow + c0 + 4);
        f[0] = (short)f2bf(u.x); f[1] = (short)f2bf(u.y);
        f[2] = (short)f2bf(u.z); f[3] = (short)f2bf(u.w);
        f[4] = (short)f2bf(v.x); f[5] = (short)f2bf(v.y);
        f[6] = (short)f2bf(v.z); f[7] = (short)f2bf(v.w);
      } else {
#pragma unroll
        for (int j = 0; j < 8; ++j) f[j] = 0;
      }
      Bf[nt][ks] = f;
    }
  }

  float ss[5], sq[5];
#pragma unroll
  for (int i = 0; i < 5; ++i) { ss[i] = 0.f; sq[i] = 0.f; }

#pragma unroll 1
  for (int t = 0; t < 4; ++t) {
    int tile = blockIdx.x * 16 + w * 4 + t;
    int item = tile * 16 + m;
    int bn = item / 20;
    int b = bn >> 12;
    int nb = idxb[item];
    const float* fme = feat + (size_t)bn * CFEAT;
    const float* fnb = feat + ((size_t)b * NN + nb) * CFEAT;
    float4 pm = xyz4[bn];
    float4 pn = xyz4[(size_t)b * NN + nb];
    float rx = pn.x - pm.x, ry = pn.y - pm.y, rz = pn.z - pm.z;

    f32x4 acc[7];
#pragma unroll
    for (int nt = 0; nt < 7; ++nt)
#pragma unroll
      for (int r = 0; r < 4; ++r) acc[nt][r] = 0.f;

#pragma unroll
    for (int ks = 0; ks < 5; ++ks) {
      int c0 = ks * 32 + quad * 8;
      bf16x8 A;
      if (c0 < 64) {
        float4 a0 = *(const float4*)(fnb + c0);
        float4 a1 = *(const float4*)(fnb + c0 + 4);
        float4 m0 = *(const float4*)(fme + c0);
        float4 m1 = *(const float4*)(fme + c0 + 4);
        A[0] = (short)f2bf(a0.x - m0.x); A[1] = (short)f2bf(a0.y - m0.y);
        A[2] = (short)f2bf(a0.z - m0.z); A[3] = (short)f2bf(a0.w - m0.w);
        A[4] = (short)f2bf(a1.x - m1.x); A[5] = (short)f2bf(a1.y - m1.y);
        A[6] = (short)f2bf(a1.z - m1.z); A[7] = (short)f2bf(a1.w - m1.w);
      } else if (c0 < 128) {
        int c = c0 - 64;
        float4 m0 = *(const float4*)(fme + c);
        float4 m1 = *(const float4*)(fme + c + 4);
        A[0] = (short)f2bf(m0.x); A[1] = (short)f2bf(m0.y);
        A[2] = (short)f2bf(m0.z); A[3] = (short)f2bf(m0.w);
        A[4] = (short)f2bf(m1.x); A[5] = (short)f2bf(m1.y);
        A[6] = (short)f2bf(m1.z); A[7] = (short)f2bf(m1.w);
      } else if (c0 < 144) {
        int v0 = c0 - 128;
#pragma unroll
        for (int j = 0; j < 8; ++j) {
          float pv = fmaf(Wh[(v0 + j) * 3], rx,
                     fmaf(Wh[(v0 + j) * 3 + 1], ry, Wh[(v0 + j) * 3 + 2] * rz));
          A[j] = (short)f2bf(pv);
        }
      } else {
#pragma unroll
        for (int j = 0; j < 8; ++j) A[j] = 0;
      }
#pragma unroll
      for (int nt = 0; nt < 7; ++nt)
        acc[nt] = __builtin_amdgcn_mfma_f32_16x16x32_bf16(A, Bf[nt][ks], acc[nt], 0, 0, 0);
    }

#pragma unroll
    for (int nt = 0; nt < 5; ++nt)
#pragma unroll
      for (int r = 0; r < 4; ++r) {
        float v = acc[nt][r];
        ss[nt] += v; sq[nt] += v * v;
      }

    // wave-private LDS transpose (no barrier needed)
#pragma unroll
    for (int nt = 0; nt < 7; ++nt)
#pragma unroll
      for (int r = 0; r < 4; ++r)
        lds[w][quad * 4 + r][nt * 16 + m] = f2bf(acc[nt][r]);

    {
      int it = lane >> 2, sg = lane & 3;
      const uint4* sp = (const uint4*)&lds[w][it][sg * 16];
      uint4 d0 = sp[0], d1 = sp[1];
      *(uint4*)(t1g + (size_t)tile * 1024 + lane * 16) = d0;
      *(uint4*)(t1g + (size_t)tile * 1024 + lane * 16 + 8) = d1;
      const uint4* spk = (const uint4*)&lds[w][it][80 + sg * 8];
      *(uint4*)(akg + (size_t)tile * 512 + lane * 8) = spk[0];
      if (lane < 32) {
        const uint4* spv = (const uint4*)&lds[w][lane >> 1][64 + (lane & 1) * 8];
        *(uint4*)(tvg + (size_t)tile * 256 + lane * 8) = spv[0];
      }
    }
  }

  float* slot = st1 + (blockIdx.x & 63) * 160;
#pragma unroll
  for (int nt = 0; nt < 5; ++nt) {
    float s = ss[nt];
    s += __shfl_xor(s, 16); s += __shfl_xor(s, 32);
    float q = sq[nt];
    q += __shfl_xor(q, 16); q += __shfl_xor(q, 32);
    if (lane < 16) {
      if (nt < 4) {
        atomicAdd(&slot[nt * 16 + lane], s);
        atomicAdd(&slot[64 + nt * 16 + lane], q);
      } else {
        atomicAdd(&slot[128 + lane], s);
        atomicAdd(&slot[144 + lane], q);
      }
    }
  }
}

// GEMM2: wave-private LDS -> no barrier
__global__ void __launch_bounds__(256) k_g2(
    const ushort_t* __restrict__ t1g, const float* __restrict__ W2,
    const float* __restrict__ par, float* __restrict__ st2,
    float* __restrict__ fqpre)
{
  __shared__ ushort_t lds[4][80][68];
  int tid = threadIdx.x;
  int w = tid >> 6, lane = tid & 63;
  int m = lane & 15, quad = lane >> 4;
  int gw = blockIdx.x * 4 + w;

  bf16x8 Bf[4][2];
#pragma unroll
  for (int nt = 0; nt < 4; ++nt) {
    const float* wrow = W2 + (nt * 16 + m) * CHN;
#pragma unroll
    for (int ks = 0; ks < 2; ++ks) {
      int c0 = ks * 32 + quad * 8;
      float4 u = *(const float4*)(wrow + c0);
      float4 v = *(const float4*)(wrow + c0 + 4);
      bf16x8 f;
      f[0] = (short)f2bf(u.x); f[1] = (short)f2bf(u.y);
      f[2] = (short)f2bf(u.z); f[3] = (short)f2bf(u.w);
      f[4] = (short)f2bf(v.x); f[5] = (short)f2bf(v.y);
      f[6] = (short)f2bf(v.z); f[7] = (short)f2bf(v.w);
      Bf[nt][ks] = f;
    }
  }
  float pa[2][8], pb[2][8];
#pragma unroll
  for (int ks = 0; ks < 2; ++ks) {
    int c0 = ks * 32 + quad * 8;
    float4 a0 = *(const float4*)(par + c0);
    float4 a1 = *(const float4*)(par + c0 + 4);
    float4 b0 = *(const float4*)(par + 64 + c0);
    float4 b1 = *(const float4*)(par + 64 + c0 + 4);
    pa[ks][0] = a0.x; pa[ks][1] = a0.y; pa[ks][2] = a0.z; pa[ks][3] = a0.w;
    pa[ks][4] = a1.x; pa[ks][5] = a1.y; pa[ks][6] = a1.z; pa[ks][7] = a1.w;
    pb[ks][0] = b0.x; pb[ks][1] = b0.y; pb[ks][2] = b0.z; pb[ks][3] = b0.w;
    pb[ks][4] = b1.x; pb[ks][5] = b1.y; pb[ks][6] = b1.z; pb[ks][7] = b1.w;
  }

  float ss[4] = {0.f, 0.f, 0.f, 0.f}, sq[4] = {0.f, 0.f, 0.f, 0.f};

#pragma unroll 1
  for (int t5 = 0; t5 < 5; ++t5) {
    int tile = gw * 5 + t5;
    int item = tile * 16 + m;
    f32x4 acc[4];
#pragma unroll
    for (int nt = 0; nt < 4; ++nt)
#pragma unroll
      for (int r = 0; r < 4; ++r) acc[nt][r] = 0.f;
#pragma unroll
    for (int ks = 0; ks < 2; ++ks) {
      const ushort_t* tp = t1g + (size_t)item * 64 + ks * 32 + quad * 8;
      uint4 raw = *(const uint4*)tp;
      unsigned rw[4] = {raw.x, raw.y, raw.z, raw.w};
      bf16x8 A;
#pragma unroll
      for (int i = 0; i < 4; ++i) {
        float lo = bf2f((ushort_t)(rw[i] & 0xffffu));
        float hi = bf2f((ushort_t)(rw[i] >> 16));
        float h0 = fmaxf(fmaf(lo, pa[ks][2 * i], pb[ks][2 * i]), 0.f);
        float h1 = fmaxf(fmaf(hi, pa[ks][2 * i + 1], pb[ks][2 * i + 1]), 0.f);
        A[2 * i] = (short)f2bf(h0);
        A[2 * i + 1] = (short)f2bf(h1);
      }
#pragma unroll
      for (int nt = 0; nt < 4; ++nt)
        acc[nt] = __builtin_amdgcn_mfma_f32_16x16x32_bf16(A, Bf[nt][ks], acc[nt], 0, 0, 0);
    }
#pragma unroll
    for (int nt = 0; nt < 4; ++nt)
#pragma unroll
      for (int r = 0; r < 4; ++r) {
        float v = acc[nt][r];
        ss[nt] += v; sq[nt] += v * v;
        lds[w][t5 * 16 + quad * 4 + r][nt * 16 + m] = f2bf(v);
      }
  }
  // wave-private: no barrier

  {
    int bnl = lane >> 4;
    int chb = (lane & 15) * 4;
    float mx0 = -3.4e38f, mx1 = -3.4e38f, mx2 = -3.4e38f, mx3 = -3.4e38f;
    float mn0 = 3.4e38f, mn1 = 3.4e38f, mn2 = 3.4e38f, mn3 = 3.4e38f;
#pragma unroll
    for (int j = 0; j < KK; ++j) {
      const uint2 rv = *(const uint2*)&lds[w][bnl * 20 + j][chb];
      float v0 = bf2f((ushort_t)(rv.x & 0xffffu));
      float v1 = bf2f((ushort_t)(rv.x >> 16));
      float v2 = bf2f((ushort_t)(rv.y & 0xffffu));
      float v3 = bf2f((ushort_t)(rv.y >> 16));
      mx0 = fmaxf(mx0, v0); mn0 = fminf(mn0, v0);
      mx1 = fmaxf(mx1, v1); mn1 = fminf(mn1, v1);
      mx2 = fmaxf(mx2, v2); mn2 = fminf(mn2, v2);
      mx3 = fmaxf(mx3, v3); mn3 = fminf(mn3, v3);
    }
    int bn = gw * 4 + bnl;
    *(float4*)(fqpre + (size_t)bn * 128 + chb) = make_float4(mx0, mx1, mx2, mx3);
    *(float4*)(fqpre + (size_t)bn * 128 + 64 + chb) = make_float4(mn0, mn1, mn2, mn3);
  }

  float* slot = st2 + (blockIdx.x & 63) * 128;
#pragma unroll
  for (int nt = 0; nt < 4; ++nt) {
    float s = ss[nt];
    s += __shfl_xor(s, 16); s += __shfl_xor(s, 32);
    float q = sq[nt];
    q += __shfl_xor(q, 16); q += __shfl_xor(q, 32);
    if (lane < 16) {
      atomicAdd(&slot[nt * 16 + lane], s);
      atomicAdd(&slot[64 + nt * 16 + lane], q);
    }
  }
}

// softmax over k + kv from cached ak/tv
#define P3P 16
__global__ void __launch_bounds__(320, 2) k_p3s(
    const ushort_t* __restrict__ akg, const ushort_t* __restrict__ tvg,
    const float* __restrict__ par, __hip_bfloat16* __restrict__ kvg)
{
  __shared__ float sl[P3P][KK][DKK + 1];
  __shared__ float sv[P3P][KK][DVV + 1];
  __shared__ float sm[P3P][DKK], ssi[P3P][DKK];
  int tid = threadIdx.x;
  int p = tid / KK, k = tid - p * KK;
  size_t item = (size_t)(blockIdx.x * P3P + p) * KK + k;
  const unsigned* ap = (const unsigned*)(akg + item * DKK);
#pragma unroll
  for (int i = 0; i < DKK / 2; ++i) {
    unsigned wv = ap[i];
    sl[p][k][2 * i]     = __uint_as_float(wv << 16);
    sl[p][k][2 * i + 1] = __uint_as_float(wv & 0xffff0000u);
  }
  const unsigned* vp = (const unsigned*)(tvg + item * DVV);
#pragma unroll
  for (int i = 0; i < DVV / 2; ++i) {
    unsigned wv = vp[i];
    float lo = __uint_as_float(wv << 16);
    float hi = __uint_as_float(wv & 0xffff0000u);
    sv[p][k][2 * i]     = fmaf(lo, par[128 + 2 * i],     par[144 + 2 * i]);
    sv[p][k][2 * i + 1] = fmaf(hi, par[128 + 2 * i + 1], par[144 + 2 * i + 1]);
  }
  __syncthreads();
  for (int pd = tid; pd < P3P * DKK; pd += 320) {
    int pp = pd >> 5, d = pd & 31;
    float m = -1e30f;
#pragma unroll
    for (int q = 0; q < KK; ++q) m = fmaxf(m, sl[pp][q][d]);
    float S = 0.f;
#pragma unroll
    for (int q = 0; q < KK; ++q) S += __expf(sl[pp][q][d] - m);
    sm[pp][d] = m; ssi[pp][d] = 1.f / S;
  }
  __syncthreads();
  for (int pd = tid; pd < P3P * DKK; pd += 320) {
    int pp = pd >> 5, d = pd & 31;
    float m = sm[pp][d], Si = ssi[pp][d];
    float a[DVV];
#pragma unroll
    for (int v = 0; v < DVV; ++v) a[v] = 0.f;
#pragma unroll
    for (int q = 0; q < KK; ++q) {
      float wgt = __expf(sl[pp][q][d] - m) * Si;
#pragma unroll
      for (int v = 0; v < DVV; ++v) a[v] = fmaf(wgt, sv[pp][q][v], a[v]);
    }
    __hip_bfloat162* dst = (__hip_bfloat162*)
        (kvg + ((size_t)(blockIdx.x * P3P + pp) * DKK + d) * DVV);
#pragma unroll
    for (int v = 0; v < DVV; v += 2) {
      float2 f2; f2.x = a[v]; f2.y = a[v + 1];
      dst[v >> 1] = __float22bfloat162_rn(f2);
    }
  }
}

// MFMA GEMM: q2 = Wq @ fq, fq reconstructed inline from fqpre (sign-aware).
__global__ void __launch_bounds__(256) k_gq(
    const float* __restrict__ fqpre, const float* __restrict__ Wq,
    const float* __restrict__ par, float* __restrict__ stq,
    float* __restrict__ q2g)
{
  int tid = threadIdx.x;
  int w = tid >> 6, lane = tid & 63;
  int m = lane & 15, quad = lane >> 4;
  int nt0 = (w & 1) * 8;
  int mt = blockIdx.x * 2 + (w >> 1);

  bf16x8 Bf[8][2];
#pragma unroll
  for (int nt = 0; nt < 8; ++nt) {
    const float* wrow = Wq + ((nt0 + nt) * 16 + m) * CHN;
#pragma unroll
    for (int ks = 0; ks < 2; ++ks) {
      int c0 = ks * 32 + quad * 8;
      float4 u = *(const float4*)(wrow + c0);
      float4 v = *(const float4*)(wrow + c0 + 4);
      bf16x8 f;
      f[0] = (short)f2bf(u.x); f[1] = (short)f2bf(u.y);
      f[2] = (short)f2bf(u.z); f[3] = (short)f2bf(u.w);
      f[4] = (short)f2bf(v.x); f[5] = (short)f2bf(v.y);
      f[6] = (short)f2bf(v.z); f[7] = (short)f2bf(v.w);
      Bf[nt][ks] = f;
    }
  }

  f32x4 acc[8];
#pragma unroll
  for (int nt = 0; nt < 8; ++nt)
#pragma unroll
    for (int r = 0; r < 4; ++r) acc[nt][r] = 0.f;

  int item = mt * 16 + m;
  const float* fp = fqpre + (size_t)item * 128;
#pragma unroll
  for (int ks = 0; ks < 2; ++ks) {
    int c0 = ks * 32 + quad * 8;
    float mxv[8], mnv[8], av[8], bv[8];
    *(float4*)&mxv[0] = *(const float4*)(fp + c0);
    *(float4*)&mxv[4] = *(const float4*)(fp + c0 + 4);
    *(float4*)&mnv[0] = *(const float4*)(fp + 64 + c0);
    *(float4*)&mnv[4] = *(const float4*)(fp + 64 + c0 + 4);
    *(float4*)&av[0] = *(const float4*)(par + 160 + c0);
    *(float4*)&av[4] = *(const float4*)(par + 160 + c0 + 4);
    *(float4*)&bv[0] = *(const float4*)(par + 224 + c0);
    *(float4*)&bv[4] = *(const float4*)(par + 224 + c0 + 4);
    bf16x8 A;
#pragma unroll
    for (int j = 0; j < 8; ++j) {
      float pick = (av[j] >= 0.f) ? mxv[j] : mnv[j];
      float fq = fmaxf(fmaf(av[j], pick, bv[j]), 0.f);
      A[j] = (short)f2bf(fq);
    }
#pragma unroll
    for (int nt = 0; nt < 8; ++nt)
      acc[nt] = __builtin_amdgcn_mfma_f32_16x16x32_bf16(A, Bf[nt][ks], acc[nt], 0, 0, 0);
  }

  float* slot = stq + (blockIdx.x & 63) * 512;
#pragma unroll
  for (int nt = 0; nt < 8; ++nt) {
    int o = (nt0 + nt) * 16 + m;
    float s = 0.f, q = 0.f;
#pragma unroll
    for (int r = 0; r < 4; ++r) {
      float v = acc[nt][r];
      q2g[(size_t)(mt * 16 + quad * 4 + r) * NQC + o] = v;
      s += v; q += v * v;
    }
    s += __shfl_xor(s, 16); s += __shfl_xor(s, 32);
    q += __shfl_xor(q, 16); q += __shfl_xor(q, 32);
    if (lane < 16) {
      atomicAdd(&slot[(nt0 + nt) * 16 + lane], s);
      atomicAdd(&slot[256 + (nt0 + nt) * 16 + lane], q);
    }
  }
}

__global__ void k_redq(const float* __restrict__ stq, const float* __restrict__ gq,
                       const float* __restrict__ bq, float* __restrict__ par)
{
  int o = threadIdx.x; // 256
  float s = 0.f, s2 = 0.f;
  for (int j = 0; j < 64; ++j) { s += stq[j * 512 + o]; s2 += stq[j * 512 + 256 + o]; }
  const float inv = 1.f / (float)BNTOT;
  float mu = s * inv, var = s2 * inv - mu * mu;
  float a = gq[o] * rsqrtf(var + EPSV);
  par[288 + o] = a; par[544 + o] = bq[o] - mu * a;
}

// coalesced attention combine
__global__ void __launch_bounds__(256) k_p4(const float* __restrict__ q2g,
                                            const __hip_bfloat16* __restrict__ kvg,
                                            const float* __restrict__ par,
                                            float* __restrict__ outp)
{
  __shared__ float sq2[NQC][33];
  __shared__ unsigned skv[NQC][33];
  int t = threadIdx.x;
  int b = blockIdx.x >> 7, nc = blockIdx.x & 127;
  int bn0 = (b << 12) | (nc << 5);
#pragma unroll 4
  for (int i = t; i < 32 * NQC; i += 256) {
    int n = i >> 8, o = i & 255;
    float q = q2g[(size_t)(bn0 + n) * NQC + o];
    sq2[o][n] = fmaxf(fmaf(q, par[288 + o], par[544 + o]), 0.f);
  }
  const unsigned* kvp = (const unsigned*)kvg;
#pragma unroll 4
  for (int i = t; i < 32 * 256; i += 256) {
    int n = i >> 8, dv2 = i & 255;
    skv[dv2][n] = kvp[(size_t)(bn0 + n) * 256 + dv2];
  }
  __syncthreads();
  int n = t & 31, h = t >> 5;
  float qr[DKK];
#pragma unroll
  for (int d = 0; d < DKK; ++d) qr[d] = sq2[h * DKK + d][n];
  int n_out = (nc << 5) + n;
  size_t ob = (size_t)BNTOT * 3 + (size_t)(b * 128 + h * 16) * NN + n_out;
#pragma unroll
  for (int vv = 0; vv < DVV; vv += 2) {
    float a0 = 0.f, a1 = 0.f;
#pragma unroll
    for (int d = 0; d < DKK; ++d) {
      unsigned pk = skv[(d * DVV + vv) >> 1][n];
      a0 = fmaf(qr[d], bf2f((ushort_t)(pk & 0xffffu)), a0);
      a1 = fmaf(qr[d], bf2f((ushort_t)(pk >> 16)), a1);
    }
    outp[ob + (size_t)vv * NN] = a0;
    outp[ob + (size_t)(vv + 1) * NN] = a1;
  }
}

// ---------- FALLBACK (round-5 proven path) ----------

__global__ void __launch_bounds__(256, 3) k_s1f(
    const float4* __restrict__ xyz4, const float* __restrict__ feat,
    const int* __restrict__ idxb, const float* __restrict__ W1,
    const float* __restrict__ Wv, const float* __restrict__ Wh,
    float* __restrict__ st1,
    __hip_bfloat16* __restrict__ t1g, __hip_bfloat16* __restrict__ tvg)
{
  int t = blockIdx.x * 256 + threadIdx.x;
  int bn = t / KK, k = t - bn * KK, b = bn >> 12;
  int nb = idxb[(size_t)bn * KK + k];
  const float* fme = feat + (size_t)bn * CFEAT;
  const float* fnb = feat + ((size_t)b * NN + nb) * CFEAT;
  float4 pn = xyz4[(size_t)b * NN + nb];
  float4 pm = xyz4[bn];
  float rx = pn.x - pm.x, ry = pn.y - pm.y, rz = pn.z - pm.z;
  float a1[CHN], av[DVV];
#pragma unroll
  for (int o = 0; o < CHN; ++o) a1[o] = 0.f;
#pragma unroll
  for (int o = 0; o < DVV; ++o) av[o] = 0.f;
#pragma unroll 1
  for (int ch = 0; ch < 9; ++ch) {
    float fc[16];
    build_chunk(ch, fme, fnb, rx, ry, rz, Wh, fc);
    accum_chunk<CHN>(W1, ch, fc, a1);
    accum_chunk<DVV>(Wv, ch, fc, av);
  }
  __hip_bfloat162* t1p = (__hip_bfloat162*)(t1g + (size_t)t * CHN);
#pragma unroll
  for (int o = 0; o < CHN; o += 2) {
    float2 f2; f2.x = a1[o]; f2.y = a1[o + 1];
    t1p[o >> 1] = __float22bfloat162_rn(f2);
  }
  __hip_bfloat162* tvp = (__hip_bfloat162*)(tvg + (size_t)t * DVV);
#pragma unroll
  for (int o = 0; o < DVV; o += 2) {
    float2 f2; f2.x = av[o]; f2.y = av[o + 1];
    tvp[o >> 1] = __float22bfloat162_rn(f2);
  }
  float* slot = st1 + (blockIdx.x & 63) * 160;
  int lane = threadIdx.x & 63;
#pragma unroll
  for (int o = 0; o < CHN; ++o) {
    float s = wred(a1[o]), s2 = wred(a1[o] * a1[o]);
    if (lane == 0) { atomicAdd(&slot[o], s); atomicAdd(&slot[CHN + o], s2); }
  }
#pragma unroll
  for (int o = 0; o < DVV; ++o) {
    float s = wred(av[o]), s2 = wred(av[o] * av[o]);
    if (lane == 0) { atomicAdd(&slot[128 + o], s); atomicAdd(&slot[128 + DVV + o], s2); }
  }
}

__global__ void __launch_bounds__(256, 4) k_skf(
    const float4* __restrict__ xyz4, const float* __restrict__ feat,
    const int* __restrict__ idxb, const float* __restrict__ Wk,
    const float* __restrict__ Wh, __hip_bfloat16* __restrict__ akg)
{
  int t = blockIdx.x * 256 + threadIdx.x;
  int bn = t / KK, k = t - bn * KK, b = bn >> 12;
  int nb = idxb[(size_t)bn * KK + k];
  const float* fme = feat + (size_t)bn * CFEAT;
  const float* fnb = feat + ((size_t)b * NN + nb) * CFEAT;
  float4 pn = xyz4[(size_t)b * NN + nb];
  float4 pm = xyz4[bn];
  float rx = pn.x - pm.x, ry = pn.y - pm.y, rz = pn.z - pm.z;
  float ak[DKK];
#pragma unroll
  for (int o = 0; o < DKK; ++o) ak[o] = 0.f;
#pragma unroll 1
  for (int ch = 0; ch < 9; ++ch) {
    float fc[16];
    build_chunk(ch, fme, fnb, rx, ry, rz, Wh, fc);
    accum_chunk<DKK>(Wk, ch, fc, ak);
  }
  __hip_bfloat162* akp = (__hip_bfloat162*)(akg + (size_t)t * DKK);
#pragma unroll
  for (int o = 0; o < DKK; o += 2) {
    float2 f2; f2.x = ak[o]; f2.y = ak[o + 1];
    akp[o >> 1] = __float22bfloat162_rn(f2);
  }
}

__global__ void __launch_bounds__(256, 4) k_s2f(
    const __hip_bfloat16* __restrict__ t1g, const float* __restrict__ W2,
    const float* __restrict__ par, float* __restrict__ st2)
{
  int t = blockIdx.x * 256 + threadIdx.x;
  const unsigned* tp = (const unsigned*)(t1g + (size_t)t * CHN);
  float h1[CHN];
#pragma unroll
  for (int i = 0; i < CHN / 2; ++i) {
    unsigned w = tp[i];
    float lo = __uint_as_float(w << 16);
    float hi = __uint_as_float(w & 0xffff0000u);
    h1[2 * i]     = fmaxf(fmaf(lo, par[2 * i],     par[64 + 2 * i]),     0.f);
    h1[2 * i + 1] = fmaxf(fmaf(hi, par[2 * i + 1], par[64 + 2 * i + 1]), 0.f);
  }
  float* slot = st2 + (blockIdx.x & 63) * 128;
  int lane = threadIdx.x & 63;
#pragma unroll 1
  for (int o = 0; o < CHN; ++o) {
    const float* w = W2 + o * CHN;
    float c0 = 0.f, c1 = 0.f, c2 = 0.f, c3 = 0.f;
#pragma unroll
    for (int c = 0; c < CHN; c += 4) {
      c0 = fmaf(w[c + 0], h1[c + 0], c0); c1 = fmaf(w[c + 1], h1[c + 1], c1);
      c2 = fmaf(w[c + 2], h1[c + 2], c2); c3 = fmaf(w[c + 3], h1[c + 3], c3);
    }
    float v = (c0 + c1) + (c2 + c3);
    float s = wred(v), s2 = wred(v * v);
    if (lane == 0) { atomicAdd(&slot[o], s); atomicAdd(&slot[64 + o], s2); }
  }
}

__global__ void __launch_bounds__(320, 2) k_p3f(
    const __hip_bfloat16* __restrict__ t1g, const __hip_bfloat16* __restrict__ akg,
    const __hip_bfloat16* __restrict__ tvg, const float* __restrict__ W2,
    const float* __restrict__ par, float* __restrict__ fqg,
    __hip_bfloat16* __restrict__ kvg)
{
  __shared__ float sl[P3P][KK][DKK + 1];
  __shared__ float sv[P3P][KK][DVV + 1];
  __shared__ unsigned sfq[P3P][CHN];
  __shared__ float sm[P3P][DKK], ssi[P3P][DKK];
  int tid = threadIdx.x;
  for (int i = tid; i < P3P * CHN; i += 320) ((unsigned*)sfq)[i] = 0u;
  __syncthreads();
  int p = tid / KK, k = tid - p * KK;
  size_t item = (size_t)(blockIdx.x * P3P + p) * KK + k;
  const unsigned* ap = (const unsigned*)(akg + item * DKK);
#pragma unroll
  for (int i = 0; i < DKK / 2; ++i) {
    unsigned w = ap[i];
    sl[p][k][2 * i]     = __uint_as_float(w << 16);
    sl[p][k][2 * i + 1] = __uint_as_float(w & 0xffff0000u);
  }
  const unsigned* vp = (const unsigned*)(tvg + item * DVV);
#pragma unroll
  for (int i = 0; i < DVV / 2; ++i) {
    unsigned w = vp[i];
    float lo = __uint_as_float(w << 16);
    float hi = __uint_as_float(w & 0xffff0000u);
    sv[p][k][2 * i]     = fmaf(lo, par[128 + 2 * i],     par[144 + 2 * i]);
    sv[p][k][2 * i + 1] = fmaf(hi, par[128 + 2 * i + 1], par[144 + 2 * i + 1]);
  }
  const unsigned* tp = (const unsigned*)(t1g + item * CHN);
  float h1[CHN];
#pragma unroll
  for (int i = 0; i < CHN / 2; ++i) {
    unsigned w = tp[i];
    float lo = __uint_as_float(w << 16);
    float hi = __uint_as_float(w & 0xffff0000u);
    h1[2 * i]     = fmaxf(fmaf(lo, par[2 * i],     par[64 + 2 * i]),     0.f);
    h1[2 * i + 1] = fmaxf(fmaf(hi, par[2 * i + 1], par[64 + 2 * i + 1]), 0.f);
  }
#pragma unroll 1
  for (int o = 0; o < CHN; ++o) {
    const float* w = W2 + o * CHN;
    float c0 = 0.f, c1 = 0.f, c2 = 0.f, c3 = 0.f;
#pragma unroll
    for (int c = 0; c < CHN; c += 4) {
      c0 = fmaf(w[c + 0], h1[c + 0], c0); c1 = fmaf(w[c + 1], h1[c + 1], c1);
      c2 = fmaf(w[c + 2], h1[c + 2], c2); c3 = fmaf(w[c + 3], h1[c + 3], c3);
    }
    float v = (c0 + c1) + (c2 + c3);
    float h2 = fmaxf(fmaf(v, par[160 + o], par[224 + o]), 0.f);
    atomicMax(&sfq[p][o], __float_as_uint(h2));
  }
  __syncthreads();
  for (int i = tid; i < P3P * CHN; i += 320)
    fqg[(size_t)blockIdx.x * (P3P * CHN) + i] = __uint_as_float(sfq[i >> 6][i & 63]);
  for (int pd = tid; pd < P3P * DKK; pd += 320) {
    int pp = pd >> 5, d = pd & 31;
    float m = -1e30f;
#pragma unroll
    for (int q = 0; q < KK; ++q) m = fmaxf(m, sl[pp][q][d]);
    float S = 0.f;
#pragma unroll
    for (int q = 0; q < KK; ++q) S += __expf(sl[pp][q][d] - m);
    sm[pp][d] = m; ssi[pp][d] = 1.f / S;
  }
  __syncthreads();
  for (int pd = tid; pd < P3P * DKK; pd += 320) {
    int pp = pd >> 5, d = pd & 31;
    float m = sm[pp][d], Si = ssi[pp][d];
    float a[DVV];
#pragma unroll
    for (int v = 0; v < DVV; ++v) a[v] = 0.f;
#pragma unroll
    for (int q = 0; q < KK; ++q) {
      float wgt = __expf(sl[pp][q][d] - m) * Si;
#pragma unroll
      for (int v = 0; v < DVV; ++v) a[v] = fmaf(wgt, sv[pp][q][v], a[v]);
    }
    __hip_bfloat162* dst = (__hip_bfloat162*)
        (kvg + ((size_t)(blockIdx.x * P3P + pp) * DKK + d) * DVV);
#pragma unroll
    for (int v = 0; v < DVV; v += 2) {
      float2 f2; f2.x = a[v]; f2.y = a[v + 1];
      dst[v >> 1] = __float22bfloat162_rn(f2);
    }
  }
}

__global__ void __launch_bounds__(128, 2) k_pqf(const float* __restrict__ fqg,
                                                const float* __restrict__ Wq,
                                                float* __restrict__ stq,
                                                float* __restrict__ q2g)
{
  int bn = blockIdx.x * 128 + threadIdx.x;
  float fq[CHN];
#pragma unroll
  for (int c = 0; c < CHN; c += 4) {
    float4 v4 = *(const float4*)(fqg + (size_t)bn * CHN + c);
    fq[c] = v4.x; fq[c + 1] = v4.y; fq[c + 2] = v4.z; fq[c + 3] = v4.w;
  }
  float* slot = stq + (blockIdx.x & 63) * 512;
  int lane = threadIdx.x & 63;
#pragma unroll 1
  for (int o = 0; o < NQC; ++o) {
    const float* w = Wq + o * CHN;
    float a0 = 0.f, a1 = 0.f, a2 = 0.f, a3 = 0.f;
#pragma unroll
    for (int c = 0; c < CHN; c += 4) {
      a0 = fmaf(w[c], fq[c], a0); a1 = fmaf(w[c + 1], fq[c + 1], a1);
      a2 = fmaf(w[c + 2], fq[c + 2], a2); a3 = fmaf(w[c + 3], fq[c + 3], a3);
    }
    float v = (a0 + a1) + (a2 + a3);
    q2g[(size_t)bn * NQC + o] = v;
    float s = wred(v), s2 = wred(v * v);
    if (lane == 0) { atomicAdd(&slot[o], s); atomicAdd(&slot[256 + o], s2); }
  }
}

__global__ void __launch_bounds__(64) k_p4f(const float* __restrict__ q2g,
                                            const __hip_bfloat16* __restrict__ kvg,
                                            const float* __restrict__ par,
                                            float* __restrict__ outp)
{
  __shared__ float sq2[NQC], skv[DKK * DVV];
  int t = threadIdx.x;
  int b = blockIdx.x & 7, n = blockIdx.x >> 3;
  int bn = (b << 12) | n;
#pragma unroll
  for (int j = 0; j < 8; ++j)
    skv[t + 64 * j] = __bfloat162float(kvg[(size_t)bn * 512 + t + 64 * j]);
#pragma unroll
  for (int j = 0; j < 4; ++j) {
    int o = t + 64 * j;
    float v = q2g[(size_t)bn * NQC + o];
    sq2[o] = fmaxf(fmaf(v, par[288 + o], par[544 + o]), 0.f);
  }
  __syncthreads();
#pragma unroll
  for (int j = 0; j < 2; ++j) {
    int ch = t + 64 * j, h = ch >> 4, vv = ch & 15;
    float a = 0.f;
#pragma unroll
    for (int d = 0; d < DKK; ++d) a = fmaf(sq2[h * DKK + d], skv[d * DVV + vv], a);
    outp[(size_t)BNTOT * 3 + ((size_t)(b * 128 + ch)) * NN + n] = a;
  }
}

// ---------- launch ----------

extern "C" void kernel_launch(void* const* d_in, const int* in_sizes, int n_in,
                              void* d_out, int out_size, void* d_ws, size_t ws_size,
                              hipStream_t stream)
{
  const float* x  = (const float*)d_in[0];
  const float* W1 = (const float*)d_in[1];
  const float* g1 = (const float*)d_in[2];
  const float* b1 = (const float*)d_in[3];
  const float* W2 = (const float*)d_in[4];
  const float* g2 = (const float*)d_in[5];
  const float* b2 = (const float*)d_in[6];
  const float* Wv = (const float*)d_in[7];
  const float* gv = (const float*)d_in[8];
  const float* bv = (const float*)d_in[9];
  const float* Wk = (const float*)d_in[10];
  const float* Wq = (const float*)d_in[11];
  const float* gq = (const float*)d_in[12];
  const float* bq = (const float*)d_in[13];
  const float* Wh = (const float*)d_in[14];

  float* ws = (float*)d_ws;
  float4* xyz4 = (float4*)ws;                      // 131072
  float*  feat = ws + 131072;                      // 2097152
  int*    idxb = (int*)(ws + 2228224);             // 655360
  float*  st1  = ws + 2883584;                     // 10240
  float*  st2  = ws + 2893824;                     // 8192
  float*  stq  = ws + 2902016;                     // 32768
  float*  par  = ws + 2934784;                     // 800
  float*  fqg  = ws + 2935584;                     // 2097152
  __hip_bfloat16* kvg = (__hip_bfloat16*)(ws + 5032736);  // 8388608 fw
  float*  outp = (float*)d_out;

  ushort_t* t1g = (ushort_t*)(ws + 13421344);      // 20971520 fw
  ushort_t* akg = (ushort_t*)(ws + 34392864);      // 10485760 fw
  ushort_t* tvg = (ushort_t*)(ws + 44878624);      //  5242880 fw
  float*    fqpre = ws + 50121504;                 //  4194304 fw
  float*    q2g = ws + 13421344;                   // alias t1g (dead after k_g2)

  const size_t NEW_NEED  = (size_t)54315808 * 4;   // ~217.3 MB (MFMA path)

  hipMemsetAsync(st1, 0, (size_t)(10240 + 8192 + 32768) * sizeof(float), stream);
  k_prep<<<128, 256, 0, stream>>>(x, xyz4, feat, outp);
  k_knn <<<512, 768, 0, stream>>>(xyz4, idxb);

  if (ws_size >= NEW_NEED) {
    k_g1  <<<2560, 256, 0, stream>>>(xyz4, feat, idxb, W1, Wv, Wk, Wh, st1, t1g, akg, tvg);
    k_red1<<<1, 128, 0, stream>>>(st1, g1, b1, gv, bv, par);
    k_g2  <<<2048, 256, 0, stream>>>(t1g, W2, par, st2, fqpre);
    k_red2<<<1, 64, 0, stream>>>(st2, g2, b2, par);
    k_p3s <<<2048, 320, 0, stream>>>(akg, tvg, par, kvg);
    k_gq  <<<1024, 256, 0, stream>>>(fqpre, Wq, par, stq, q2g);
    k_redq<<<1, 256, 0, stream>>>(stq, gq, bq, par);
    k_p4  <<<1024, 256, 0, stream>>>(q2g, kvg, par, outp);
  } else {
    __hip_bfloat16* t1b = (__hip_bfloat16*)t1g;
    __hip_bfloat16* akb = (__hip_bfloat16*)akg;
    __hip_bfloat16* tvb = (__hip_bfloat16*)tvg;
    float* q2f = ws + 34392864;
    k_s1f <<<2560, 256, 0, stream>>>(xyz4, feat, idxb, W1, Wv, Wh, st1, t1b, tvb);
    k_skf <<<2560, 256, 0, stream>>>(xyz4, feat, idxb, Wk, Wh, akb);
    k_red1<<<1, 128, 0, stream>>>(st1, g1, b1, gv, bv, par);
    k_s2f <<<2560, 256, 0, stream>>>(t1b, W2, par, st2);
    k_red2<<<1, 64, 0, stream>>>(st2, g2, b2, par);
    k_p3f <<<2048, 320, 0, stream>>>(t1b, akb, tvb, W2, par, fqg, kvg);
    k_pqf <<<256, 128, 0, stream>>>(fqg, Wq, stq, q2f);
    k_redq<<<1, 256, 0, stream>>>(stq, gq, bq, par);
    k_p4f <<<32768, 64, 0, stream>>>(q2f, kvg, par, outp);
  }
}